// Round 1
// baseline (2745.173 us; speedup 1.0000x reference)
//
#include <hip/hip_runtime.h>
#include <hip/hip_bf16.h>
#include <math.h>

#define DIM 128
#define QB 64
#define MB 128
#define NSPLIT 8
#define KSEL 16

// ---------------------------------------------------------------------------
// Kernel 1: Poincare transform  P = clip_ball(tanh(X @ W^T + b)), P2 = ||P||^2
// ---------------------------------------------------------------------------
__global__ __launch_bounds__(256) void poincare_k(
    const float* __restrict__ X, int R,
    const float* __restrict__ W, const float* __restrict__ bias,
    float* __restrict__ P, float* __restrict__ P2)
{
  __shared__ float Wl[DIM * 132];   // W row-major, padded stride 132 (bank-free)
  __shared__ float xl[2 * DIM];
  __shared__ float red[4];
  const int t = threadIdx.x;

  // stage W (64KB) once per block
  for (int f4 = t; f4 < DIM * 32; f4 += 256) {
    int r = f4 >> 5, c4 = f4 & 31;
    *(float4*)&Wl[r * 132 + c4 * 4] = *(const float4*)&W[r * DIM + c4 * 4];
  }

  const int rl  = t >> 7;      // row-in-pair 0..1
  const int j   = t & 127;     // output dim
  const int wid = t >> 6;      // wave id 0..3
  const float bj = bias[j];
  const int pairs = (R + 1) >> 1;

  for (int p = blockIdx.x; p < pairs; p += gridDim.x) {
    const int row = p * 2 + rl;
    const bool valid = row < R;
    __syncthreads();                      // protect xl/red from prev iter
    xl[rl * DIM + j] = valid ? X[(size_t)row * DIM + j] : 0.0f;
    __syncthreads();

    float acc = bj;
    #pragma unroll
    for (int i4 = 0; i4 < 32; ++i4) {
      float4 xv = *(const float4*)&xl[rl * DIM + i4 * 4];
      float4 wv = *(const float4*)&Wl[j * 132 + i4 * 4];
      acc = fmaf(xv.x, wv.x, acc);
      acc = fmaf(xv.y, wv.y, acc);
      acc = fmaf(xv.z, wv.z, acc);
      acc = fmaf(xv.w, wv.w, acc);
    }
    const float h = tanhf(acc);

    float s = h * h;                       // 128-wide reduction (2 waves)
    #pragma unroll
    for (int o = 32; o > 0; o >>= 1) s += __shfl_xor(s, o);
    if ((t & 63) == 0) red[wid] = s;
    __syncthreads();
    const float norm2 = red[rl * 2] + red[rl * 2 + 1];
    const float norm  = sqrtf(norm2);
    const float scale = (norm > 0.9f) ? (0.9f / norm) : 1.0f;

    if (valid) {
      P[(size_t)row * DIM + j] = h * scale;
      if (j == 0) P2[row] = norm2 * scale * scale;
    }
  }
}

// ---------------------------------------------------------------------------
// Kernel 2: fused distance + per-(query,split) top-16
//   block: 256 threads, 64 queries; tiles of 128 mem rows; 8q x 4m per thread
//   key = (f32bits(dist) << 32) | mem_idx  -> min() == lax.top_k tie-break
// ---------------------------------------------------------------------------
__global__ __launch_bounds__(256, 1) void score_topk_k(
    const float* __restrict__ Pq, const float* __restrict__ Pq2,
    const float* __restrict__ Pm, const float* __restrict__ Pm2,
    int B, int N, unsigned long long* __restrict__ splitTop)
{
  __shared__ float ql[QB * 132];      // 33.8 KB
  __shared__ float q2l[QB];
  __shared__ float m2l[MB];
  __shared__ float dl[QB * 132];      // 33.8 KB (64 q x 128 m, padded)
  __shared__ float ml[MB * 132];      // 67.6 KB

  const int t = threadIdx.x;
  const int qb    = blockIdx.x;
  const int split = blockIdx.y;
  const int qbase = qb * QB;
  const int mlo = (int)(((long long)split * N) / NSPLIT);
  const int mhi = (int)(((long long)(split + 1) * N) / NSPLIT);

  // stage queries once
  for (int f4 = t; f4 < QB * 32; f4 += 256) {
    int r = f4 >> 5, c4 = f4 & 31;
    float4 v = make_float4(0.f, 0.f, 0.f, 0.f);
    if (qbase + r < B) v = *(const float4*)&Pq[(size_t)(qbase + r) * DIM + c4 * 4];
    *(float4*)&ql[r * 132 + c4 * 4] = v;
  }
  if (t < QB) q2l[t] = (qbase + t < B) ? Pq2[qbase + t] : 0.0f;

  const int tq = t >> 5;   // 0..7  (compute q group)
  const int tm = t & 31;   // 0..31 (compute m group)
  const int qi = t >> 2;   // 0..63 (insertion query)
  const int c0 = t & 3;

  unsigned long long keys[KSEL];
  #pragma unroll
  for (int i = 0; i < KSEL; ++i) keys[i] = ~0ull;
  unsigned long long worst = ~0ull;

  const int ntiles = (mhi - mlo + MB - 1) / MB;
  for (int tile = 0; tile < ntiles; ++tile) {
    const int mbase = mlo + tile * MB;
    __syncthreads();                       // ml/dl free from previous phase

    // stage 128 mem rows (64 KB) + their norms
    for (int f4 = t; f4 < MB * 32; f4 += 256) {
      int r = f4 >> 5, c4 = f4 & 31;
      int gr = mbase + r;
      float4 v = make_float4(0.f, 0.f, 0.f, 0.f);
      if (gr < mhi) v = *(const float4*)&Pm[(size_t)gr * DIM + c4 * 4];
      *(float4*)&ml[r * 132 + c4 * 4] = v;
    }
    if (t < MB)
      m2l[t] = (mbase + t < mhi) ? Pm2[mbase + t] : __int_as_float(0x7f800000);
    __syncthreads();

    float dot[8][4];
    #pragma unroll
    for (int a = 0; a < 8; ++a)
      #pragma unroll
      for (int b = 0; b < 4; ++b) dot[a][b] = 0.0f;

    #pragma unroll 4
    for (int i4 = 0; i4 < 32; ++i4) {
      float4 mv0 = *(const float4*)&ml[(tm      ) * 132 + i4 * 4];
      float4 mv1 = *(const float4*)&ml[(tm + 32) * 132 + i4 * 4];
      float4 mv2 = *(const float4*)&ml[(tm + 64) * 132 + i4 * 4];
      float4 mv3 = *(const float4*)&ml[(tm + 96) * 132 + i4 * 4];
      #pragma unroll
      for (int a = 0; a < 8; ++a) {
        float4 qv = *(const float4*)&ql[(tq + 8 * a) * 132 + i4 * 4];
        dot[a][0] = fmaf(qv.x, mv0.x, dot[a][0]);
        dot[a][0] = fmaf(qv.y, mv0.y, dot[a][0]);
        dot[a][0] = fmaf(qv.z, mv0.z, dot[a][0]);
        dot[a][0] = fmaf(qv.w, mv0.w, dot[a][0]);
        dot[a][1] = fmaf(qv.x, mv1.x, dot[a][1]);
        dot[a][1] = fmaf(qv.y, mv1.y, dot[a][1]);
        dot[a][1] = fmaf(qv.z, mv1.z, dot[a][1]);
        dot[a][1] = fmaf(qv.w, mv1.w, dot[a][1]);
        dot[a][2] = fmaf(qv.x, mv2.x, dot[a][2]);
        dot[a][2] = fmaf(qv.y, mv2.y, dot[a][2]);
        dot[a][2] = fmaf(qv.z, mv2.z, dot[a][2]);
        dot[a][2] = fmaf(qv.w, mv2.w, dot[a][2]);
        dot[a][3] = fmaf(qv.x, mv3.x, dot[a][3]);
        dot[a][3] = fmaf(qv.y, mv3.y, dot[a][3]);
        dot[a][3] = fmaf(qv.z, mv3.z, dot[a][3]);
        dot[a][3] = fmaf(qv.w, mv3.w, dot[a][3]);
      }
    }

    // d2 = (q2 + m2) - 2*dot  (matches reference op order), exchange via LDS
    #pragma unroll
    for (int a = 0; a < 8; ++a) {
      #pragma unroll
      for (int b = 0; b < 4; ++b) {
        const int qlc = tq + 8 * a, mlc = tm + 32 * b;
        dl[qlc * 132 + mlc] = (q2l[qlc] + m2l[mlc]) - 2.0f * dot[a][b];
      }
    }
    __syncthreads();

    // insertion: thread owns query qi, columns c0 + 4*ci
    for (int ci = 0; ci < 32; ++ci) {
      const int c = c0 + 4 * ci;
      const float d2 = dl[qi * 132 + c];
      const float dist = sqrtf(fmaxf(d2, 1e-12f));
      const unsigned long long key =
          (((unsigned long long)__float_as_uint(dist)) << 32) |
          (unsigned int)(mbase + c);
      if (key < worst) {
        int wi = 0;
        unsigned long long w = keys[0];
        #pragma unroll
        for (int i = 1; i < KSEL; ++i)
          if (keys[i] > w) { w = keys[i]; wi = i; }
        #pragma unroll
        for (int i = 0; i < KSEL; ++i) keys[i] = (i == wi) ? key : keys[i];
        w = keys[0];
        #pragma unroll
        for (int i = 1; i < KSEL; ++i) w = (keys[i] > w) ? keys[i] : w;
        worst = w;
      }
    }
  }

  // merge the 4 threads of each query via shfl (lane groups of 4), emit sorted
  for (int r = 0; r < KSEL; ++r) {
    unsigned long long mymin = keys[0];
    #pragma unroll
    for (int i = 1; i < KSEL; ++i) mymin = (keys[i] < mymin) ? keys[i] : mymin;
    unsigned long long g = mymin;
    unsigned long long o1 = __shfl_xor(g, 1, 4); g = (o1 < g) ? o1 : g;
    unsigned long long o2 = __shfl_xor(g, 2, 4); g = (o2 < g) ? o2 : g;
    #pragma unroll
    for (int i = 0; i < KSEL; ++i) keys[i] = (keys[i] == g) ? ~0ull : keys[i];
    if (c0 == 0 && (qbase + qi) < B)
      splitTop[((size_t)(qbase + qi) * NSPLIT + split) * KSEL + r] = g;
  }
}

// ---------------------------------------------------------------------------
// Kernel 3: merge splits -> final top-16, softmax weights, gather outcomes
// ---------------------------------------------------------------------------
__global__ __launch_bounds__(128) void finalize_k(
    const unsigned long long* __restrict__ splitTop,
    const float* __restrict__ memOut,
    float* __restrict__ outW, float* __restrict__ outO)
{
  const int q = blockIdx.x;
  const int t = threadIdx.x;
  __shared__ unsigned long long sel[KSEL];
  __shared__ float el[KSEL];

  if (t < 64) {
    unsigned long long a = splitTop[(size_t)q * (NSPLIT * KSEL) + t];
    unsigned long long b = splitTop[(size_t)q * (NSPLIT * KSEL) + 64 + t];
    for (int r = 0; r < KSEL; ++r) {
      unsigned long long g = (a < b) ? a : b;
      #pragma unroll
      for (int o = 1; o < 64; o <<= 1) {
        unsigned long long s = __shfl_xor(g, o);
        g = (s < g) ? s : g;
      }
      if (a == g) a = ~0ull;
      else if (b == g) b = ~0ull;
      if (t == 0) sel[r] = g;
    }
  }
  __syncthreads();

  if (t < KSEL) {
    const float d  = __uint_as_float((unsigned)(sel[t] >> 32));
    const float d0 = __uint_as_float((unsigned)(sel[0] >> 32));
    const float x  = -(d / 0.1f);
    const float x0 = -(d0 / 0.1f);   // max of the softmax inputs
    el[t] = expf(x - x0);
  }
  __syncthreads();
  if (t < KSEL) {
    float sum = 0.0f;
    #pragma unroll
    for (int i = 0; i < KSEL; ++i) sum += el[i];
    outW[(size_t)q * KSEL + t] = el[t] / sum;
  }

  for (int r = 0; r < KSEL; ++r) {
    const int idx = (int)(sel[r] & 0xffffffffu);
    outO[((size_t)q * KSEL + r) * DIM + t] = memOut[(size_t)idx * DIM + t];
  }
}

// ---------------------------------------------------------------------------
extern "C" void kernel_launch(void* const* d_in, const int* in_sizes, int n_in,
                              void* d_out, int out_size, void* d_ws, size_t ws_size,
                              hipStream_t stream)
{
  const float* query   = (const float*)d_in[0];
  const float* W       = (const float*)d_in[1];
  const float* bias    = (const float*)d_in[2];
  const float* mem_emb = (const float*)d_in[3];
  const float* mem_out = (const float*)d_in[4];
  const int B = in_sizes[0] / DIM;   // 2048
  const int N = in_sizes[3] / DIM;   // 100000

  // workspace layout (floats), all offsets 16B-aligned
  float* ws  = (float*)d_ws;
  float* Pm  = ws;                               // N*128
  float* Pm2 = Pm + (size_t)N * DIM;             // N
  float* Pq  = Pm2 + N;                          // B*128
  float* Pq2 = Pq + (size_t)B * DIM;             // B
  unsigned long long* splitTop =
      (unsigned long long*)(Pq2 + B);            // B * NSPLIT * KSEL keys

  float* outW = (float*)d_out;
  float* outO = outW + (size_t)B * KSEL;

  // 1) Poincare transforms
  poincare_k<<<dim3(1024), dim3(256), 0, stream>>>(mem_emb, N, W, bias, Pm, Pm2);
  int qblocks = (B + 1) / 2; if (qblocks > 1024) qblocks = 1024;
  poincare_k<<<dim3(qblocks), dim3(256), 0, stream>>>(query, B, W, bias, Pq, Pq2);

  // 2) fused distance + split top-16
  dim3 grid2((B + QB - 1) / QB, NSPLIT);
  score_topk_k<<<grid2, dim3(256), 0, stream>>>(Pq, Pq2, Pm, Pm2, B, N, splitTop);

  // 3) merge + softmax + gather
  finalize_k<<<dim3(B), dim3(128), 0, stream>>>(splitTop, mem_out, outW, outO);
}

// Round 2
// 1358.336 us; speedup vs baseline: 2.0210x; 2.0210x over previous
//
#include <hip/hip_runtime.h>
#include <hip/hip_bf16.h>
#include <math.h>

#define DIM 128
#define QB 64
#define MB 128
#define NSPLIT 8
#define KSEL 16
#define RESCORE 32

using bf16x8 = __attribute__((ext_vector_type(8))) short;
using f32x4  = __attribute__((ext_vector_type(4))) float;

__device__ inline unsigned short f2bf(float f) {
  __hip_bfloat16 h = __float2bfloat16(f);   // RNE
  return __builtin_bit_cast(unsigned short, h);
}

__device__ inline f32x4 mfma16(bf16x8 a, bf16x8 b, f32x4 c) {
  return __builtin_amdgcn_mfma_f32_16x16x32_bf16(a, b, c, 0, 0, 0);
}

// ---------------------------------------------------------------------------
// Kernel 1: Poincare transform  P = clip_ball(tanh(X @ W^T + b)), P2 = ||P||^2
// (identical to the round-1 passing version)
// ---------------------------------------------------------------------------
__global__ __launch_bounds__(256) void poincare_k(
    const float* __restrict__ X, int R,
    const float* __restrict__ W, const float* __restrict__ bias,
    float* __restrict__ P, float* __restrict__ P2)
{
  __shared__ float Wl[DIM * 132];
  __shared__ float xl[2 * DIM];
  __shared__ float red[4];
  const int t = threadIdx.x;

  for (int f4 = t; f4 < DIM * 32; f4 += 256) {
    int r = f4 >> 5, c4 = f4 & 31;
    *(float4*)&Wl[r * 132 + c4 * 4] = *(const float4*)&W[r * DIM + c4 * 4];
  }

  const int rl  = t >> 7;
  const int j   = t & 127;
  const int wid = t >> 6;
  const float bj = bias[j];
  const int pairs = (R + 1) >> 1;

  for (int p = blockIdx.x; p < pairs; p += gridDim.x) {
    const int row = p * 2 + rl;
    const bool valid = row < R;
    __syncthreads();
    xl[rl * DIM + j] = valid ? X[(size_t)row * DIM + j] : 0.0f;
    __syncthreads();

    float acc = bj;
    #pragma unroll
    for (int i4 = 0; i4 < 32; ++i4) {
      float4 xv = *(const float4*)&xl[rl * DIM + i4 * 4];
      float4 wv = *(const float4*)&Wl[j * 132 + i4 * 4];
      acc = fmaf(xv.x, wv.x, acc);
      acc = fmaf(xv.y, wv.y, acc);
      acc = fmaf(xv.z, wv.z, acc);
      acc = fmaf(xv.w, wv.w, acc);
    }
    const float h = tanhf(acc);

    float s = h * h;
    #pragma unroll
    for (int o = 32; o > 0; o >>= 1) s += __shfl_xor(s, o);
    if ((t & 63) == 0) red[wid] = s;
    __syncthreads();
    const float norm2 = red[rl * 2] + red[rl * 2 + 1];
    const float norm  = sqrtf(norm2);
    const float scale = (norm > 0.9f) ? (0.9f / norm) : 1.0f;

    if (valid) {
      P[(size_t)row * DIM + j] = h * scale;
      if (j == 0) P2[row] = norm2 * scale * scale;
    }
  }
}

// ---------------------------------------------------------------------------
// Kernel 2: bf16-MFMA approximate distance + per-(query,split) top-16
//   512 thr (8 waves), QB=64 queries, MB=128 mem tile, K=128.
//   Q fragments persistent in registers; M tile fp32->bf16 into XOR-swizzled
//   LDS; d^2 exchanged via LDS; 8 owner-threads/query run the top-16 stream.
//   key = (f32bits(max(d2,0)) << 32) | mem_idx   (approx; rescored in K3)
// ---------------------------------------------------------------------------
__global__ __launch_bounds__(512, 2) void score_topk_k(
    const float* __restrict__ Pq, const float* __restrict__ Pq2,
    const float* __restrict__ Pm, const float* __restrict__ Pm2,
    int B, int N, unsigned long long* __restrict__ splitTop)
{
  __shared__ __align__(16) unsigned short Ml[MB * 128];  // 32 KB swizzled bf16
  __shared__ float dl[QB * 132];                         // 33.8 KB
  __shared__ float m2l[2][MB];
  __shared__ float q2l[QB];

  const int t = threadIdx.x;
  const int split = blockIdx.x;        // x = split -> same-split blocks share XCD/L2
  const int qb    = blockIdx.y;
  const int qbase = qb * QB;
  const int lane  = t & 63;
  const int w  = t >> 6;               // wave 0..7
  const int wr = w >> 2;               // q half   (0..1)
  const int wc = w & 3;                // m quarter(0..3)

  const int mlo = (int)(((long long)split * N) / NSPLIT);
  const int mhi = (int)(((long long)(split + 1) * N) / NSPLIT);

  // persistent Q fragments (A operand): row = lane&15, k-chunk = (lane>>4)*8
  bf16x8 qf[2][4];
  #pragma unroll
  for (int s = 0; s < 2; ++s) {
    const int qrow = qbase + (wr * 2 + s) * 16 + (lane & 15);
    #pragma unroll
    for (int ks = 0; ks < 4; ++ks) {
      const float* src = &Pq[(size_t)qrow * DIM + ks * 32 + (lane >> 4) * 8];
      float4 lo = *(const float4*)src;
      float4 hi = *(const float4*)(src + 4);
      bf16x8 v;
      v[0] = (short)f2bf(lo.x); v[1] = (short)f2bf(lo.y);
      v[2] = (short)f2bf(lo.z); v[3] = (short)f2bf(lo.w);
      v[4] = (short)f2bf(hi.x); v[5] = (short)f2bf(hi.y);
      v[6] = (short)f2bf(hi.z); v[7] = (short)f2bf(hi.w);
      qf[s][ks] = v;
    }
  }
  if (t < QB) q2l[t] = Pq2[qbase + t];

  // stage one 128-row M tile: fp32 -> bf16, swizzled byte ^= (row&7)<<4
  auto stage = [&](int mbase, int buf) {
    const int r = t >> 2, quarter = t & 3;
    const size_t grow = (size_t)(mbase + r) * DIM + quarter * 32;
    char* base = (char*)Ml + r * 256;
    const int x = (r & 7) << 4;
    #pragma unroll
    for (int u = 0; u < 4; ++u) {
      float4 a = *(const float4*)&Pm[grow + u * 8];
      float4 b = *(const float4*)&Pm[grow + u * 8 + 4];
      uint4 o;
      o.x = (unsigned)f2bf(a.x) | ((unsigned)f2bf(a.y) << 16);
      o.y = (unsigned)f2bf(a.z) | ((unsigned)f2bf(a.w) << 16);
      o.z = (unsigned)f2bf(b.x) | ((unsigned)f2bf(b.y) << 16);
      o.w = (unsigned)f2bf(b.z) | ((unsigned)f2bf(b.w) << 16);
      *(uint4*)(base + ((quarter * 64 + u * 16) ^ x)) = o;
    }
    if (t < MB) {
      int gr = mbase + t;
      m2l[buf][t] = (gr < mhi) ? Pm2[gr] : __int_as_float(0x7f800000); // +inf pad
    }
  };

  stage(mlo, 0);
  __syncthreads();

  unsigned long long keys[KSEL];
  #pragma unroll
  for (int i = 0; i < KSEL; ++i) keys[i] = ~0ull;
  unsigned long long worst = ~0ull;

  const int ntiles = (mhi - mlo + MB - 1) / MB;
  const int qi = t >> 3;   // owner query 0..63
  const int c0 = t & 7;

  for (int tile = 0; tile < ntiles; ++tile) {
    const int mbase = mlo + tile * MB;
    const int cur = tile & 1;

    // ---- MFMA phase: 16 mfma/wave; B-frag rows from swizzled LDS
    f32x4 acc[2][2];
    #pragma unroll
    for (int s = 0; s < 2; ++s)
      #pragma unroll
      for (int n = 0; n < 2; ++n) acc[s][n] = (f32x4){0.f, 0.f, 0.f, 0.f};

    #pragma unroll
    for (int ks = 0; ks < 4; ++ks) {
      #pragma unroll
      for (int n = 0; n < 2; ++n) {
        const int row = (wc * 2 + n) * 16 + (lane & 15);
        const int cb  = (ks * 64 + (lane >> 4) * 16) ^ ((row & 7) << 4);
        bf16x8 bfr = *(const bf16x8*)((const char*)Ml + row * 256 + cb);
        acc[0][n] = mfma16(qf[0][ks], bfr, acc[0][n]);
        acc[1][n] = mfma16(qf[1][ks], bfr, acc[1][n]);
      }
    }

    // d2 = (q2 + m2) - 2*dot -> dl  (C/D map: col=lane&15, row=(lane>>4)*4+r)
    #pragma unroll
    for (int s = 0; s < 2; ++s) {
      const int qv = (wr * 2 + s) * 16 + ((lane >> 4) << 2);
      #pragma unroll
      for (int n = 0; n < 2; ++n) {
        const int m = (wc * 2 + n) * 16 + (lane & 15);
        const float m2 = m2l[cur][m];
        #pragma unroll
        for (int r = 0; r < 4; ++r)
          dl[(qv + r) * 132 + m] = (q2l[qv + r] + m2) - 2.0f * acc[s][n][r];
      }
    }
    __syncthreads();

    // ---- phase 2: prefetch+stage next tile; insertion scan on dl
    if (tile + 1 < ntiles) stage(mbase + MB, cur ^ 1);

    for (int ci = 0; ci < MB / 8; ++ci) {
      const int c = c0 + 8 * ci;
      const float d2 = dl[qi * 132 + c];
      const float d2c = fmaxf(d2, 0.0f);
      const unsigned long long key =
          (((unsigned long long)__float_as_uint(d2c)) << 32) |
          (unsigned)(mbase + c);
      if (key < worst) {
        int wi = 0; unsigned long long wv = keys[0];
        #pragma unroll
        for (int i = 1; i < KSEL; ++i) if (keys[i] > wv) { wv = keys[i]; wi = i; }
        #pragma unroll
        for (int i = 0; i < KSEL; ++i) keys[i] = (i == wi) ? key : keys[i];
        wv = keys[0];
        #pragma unroll
        for (int i = 1; i < KSEL; ++i) wv = (keys[i] > wv) ? keys[i] : wv;
        worst = wv;
      }
    }
    __syncthreads();
  }

  // merge the 8 owner-threads per query (shfl groups of 8), emit sorted top-16
  for (int r = 0; r < KSEL; ++r) {
    unsigned long long mymin = keys[0];
    #pragma unroll
    for (int i = 1; i < KSEL; ++i) mymin = (keys[i] < mymin) ? keys[i] : mymin;
    unsigned long long g = mymin, o;
    o = __shfl_xor(g, 1, 8); g = (o < g) ? o : g;
    o = __shfl_xor(g, 2, 8); g = (o < g) ? o : g;
    o = __shfl_xor(g, 4, 8); g = (o < g) ? o : g;
    #pragma unroll
    for (int i = 0; i < KSEL; ++i) keys[i] = (keys[i] == g) ? ~0ull : keys[i];
    if (c0 == 0)
      splitTop[((size_t)(qbase + qi) * NSPLIT + split) * KSEL + r] = g;
  }
}

// ---------------------------------------------------------------------------
// Kernel 3: merge splits -> approx top-32 -> EXACT fp32 rescore -> top-16,
//           softmax weights, gather outcomes.
// ---------------------------------------------------------------------------
__global__ __launch_bounds__(256) void finalize_k(
    const unsigned long long* __restrict__ splitTop,
    const float* __restrict__ Pq, const float* __restrict__ Pq2,
    const float* __restrict__ Pm, const float* __restrict__ Pm2,
    const float* __restrict__ memOut,
    float* __restrict__ outW, float* __restrict__ outO)
{
  const int q = blockIdx.x;
  const int t = threadIdx.x;
  __shared__ unsigned long long selA[RESCORE];
  __shared__ unsigned long long keyx[RESCORE];
  __shared__ unsigned long long selB[KSEL];
  __shared__ float el[KSEL];

  // phase A: approx top-32 of the 128 merged split candidates (wave 0)
  if (t < 64) {
    unsigned long long a = splitTop[(size_t)q * (NSPLIT * KSEL) + t];
    unsigned long long b = splitTop[(size_t)q * (NSPLIT * KSEL) + 64 + t];
    for (int r = 0; r < RESCORE; ++r) {
      unsigned long long g = (a < b) ? a : b;
      #pragma unroll
      for (int o = 1; o < 64; o <<= 1) {
        unsigned long long s = __shfl_xor(g, o);
        g = (s < g) ? s : g;
      }
      if (a == g) a = ~0ull; else if (b == g) b = ~0ull;
      if (t == 0) selA[r] = g;
    }
  }
  __syncthreads();

  // phase B: exact fp32 rescore, 8 threads per candidate
  {
    const int g = t >> 3, e = t & 7;
    const int idx = (int)(selA[g] & 0xffffffffu);
    const float4* qr = (const float4*)&Pq[(size_t)q * DIM];
    const float4* mr = (const float4*)&Pm[(size_t)idx * DIM];
    float s = 0.f;
    #pragma unroll
    for (int u = 0; u < 4; ++u) {
      float4 a = qr[e * 4 + u], b = mr[e * 4 + u];
      s = fmaf(a.x, b.x, s); s = fmaf(a.y, b.y, s);
      s = fmaf(a.z, b.z, s); s = fmaf(a.w, b.w, s);
    }
    s += __shfl_xor(s, 1, 8);
    s += __shfl_xor(s, 2, 8);
    s += __shfl_xor(s, 4, 8);
    if (e == 0) {
      float d2 = (Pq2[q] + Pm2[idx]) - 2.0f * s;
      float dist = sqrtf(fmaxf(d2, 1e-12f));
      keyx[g] = (((unsigned long long)__float_as_uint(dist)) << 32) | (unsigned)idx;
    }
  }
  __syncthreads();

  // phase C: exact top-16 of the 32 (wave 0)
  if (t < 64) {
    unsigned long long kk = (t < RESCORE) ? keyx[t] : ~0ull;
    for (int r = 0; r < KSEL; ++r) {
      unsigned long long g = kk;
      #pragma unroll
      for (int o = 1; o < 64; o <<= 1) {
        unsigned long long s = __shfl_xor(g, o);
        g = (s < g) ? s : g;
      }
      if (kk == g) kk = ~0ull;
      if (t == 0) selB[r] = g;
    }
  }
  __syncthreads();

  if (t < KSEL) {
    const float d  = __uint_as_float((unsigned)(selB[t] >> 32));
    const float d0 = __uint_as_float((unsigned)(selB[0] >> 32));
    const float x  = -(d / 0.1f);
    const float x0 = -(d0 / 0.1f);
    el[t] = expf(x - x0);
  }
  __syncthreads();
  if (t < KSEL) {
    float sum = 0.f;
    #pragma unroll
    for (int i = 0; i < KSEL; ++i) sum += el[i];
    outW[(size_t)q * KSEL + t] = el[t] / sum;
  }

  for (int f4 = t; f4 < KSEL * 32; f4 += 256) {
    int r = f4 >> 5, c4 = f4 & 31;
    int idx = (int)(selB[r] & 0xffffffffu);
    *(float4*)&outO[((size_t)q * KSEL + r) * DIM + c4 * 4] =
        *(const float4*)&memOut[(size_t)idx * DIM + c4 * 4];
  }
}

// ---------------------------------------------------------------------------
extern "C" void kernel_launch(void* const* d_in, const int* in_sizes, int n_in,
                              void* d_out, int out_size, void* d_ws, size_t ws_size,
                              hipStream_t stream)
{
  const float* query   = (const float*)d_in[0];
  const float* W       = (const float*)d_in[1];
  const float* bias    = (const float*)d_in[2];
  const float* mem_emb = (const float*)d_in[3];
  const float* mem_out = (const float*)d_in[4];
  const int B = in_sizes[0] / DIM;   // 2048
  const int N = in_sizes[3] / DIM;   // 100000
  const int N_pad = ((N + MB - 1) / MB) * MB;

  // workspace (floats): Pm[N_pad*128] | Pm2[N] | Pq[B*128] | Pq2[B] | splitTop
  float* ws  = (float*)d_ws;
  float* Pm  = ws;
  float* Pm2 = Pm + (size_t)N_pad * DIM;
  float* Pq  = Pm2 + N;
  float* Pq2 = Pq + (size_t)B * DIM;
  unsigned long long* splitTop = (unsigned long long*)(Pq2 + B);

  float* outW = (float*)d_out;
  float* outO = outW + (size_t)B * KSEL;

  // 1) Poincare transforms (fp32, exact basis for rescoring)
  poincare_k<<<dim3(1024), dim3(256), 0, stream>>>(mem_emb, N, W, bias, Pm, Pm2);
  int qblocks = (B + 1) / 2; if (qblocks > 1024) qblocks = 1024;
  poincare_k<<<dim3(qblocks), dim3(256), 0, stream>>>(query, B, W, bias, Pq, Pq2);

  // 2) bf16-MFMA approx distance + split top-16 (x = split for XCD affinity)
  dim3 grid2(NSPLIT, (B + QB - 1) / QB);
  score_topk_k<<<grid2, dim3(512), 0, stream>>>(Pq, Pq2, Pm, Pm2, B, N, splitTop);

  // 3) merge + exact rescore + softmax + gather
  finalize_k<<<dim3(B), dim3(256), 0, stream>>>(splitTop, Pq, Pq2, Pm, Pm2,
                                                mem_out, outW, outO);
}

// Round 3
// 544.389 us; speedup vs baseline: 5.0427x; 2.4952x over previous
//
#include <hip/hip_runtime.h>
#include <hip/hip_bf16.h>
#include <math.h>

#define DIM 128
#define QB 64
#define MB 128
#define NSPLIT 16
#define KSEL 16
#define RESCORE 32
#define IDXMASK 0x1FFFu
#define KEYMASK 0xFFFFE000u

using bf16x8 = __attribute__((ext_vector_type(8))) short;
using f32x4  = __attribute__((ext_vector_type(4))) float;

__device__ inline unsigned short f2bf(float f) {
  __hip_bfloat16 h = __float2bfloat16(f);   // RNE
  return __builtin_bit_cast(unsigned short, h);
}

__device__ inline f32x4 mfma16(bf16x8 a, bf16x8 b, f32x4 c) {
  return __builtin_amdgcn_mfma_f32_16x16x32_bf16(a, b, c, 0, 0, 0);
}

// ---------------------------------------------------------------------------
// Kernel 1: Poincare transform  P = clip_ball(tanh(X @ W^T + b)), P2 = ||P||^2
// Optionally also writes bf16 copy (for the MFMA scoring pass).
// ---------------------------------------------------------------------------
__global__ __launch_bounds__(256) void poincare_k(
    const float* __restrict__ X, int R,
    const float* __restrict__ W, const float* __restrict__ bias,
    float* __restrict__ P, float* __restrict__ P2,
    unsigned short* __restrict__ Pbf)
{
  __shared__ float Wl[DIM * 132];
  __shared__ float xl[2 * DIM];
  __shared__ float red[4];
  const int t = threadIdx.x;

  for (int f4 = t; f4 < DIM * 32; f4 += 256) {
    int r = f4 >> 5, c4 = f4 & 31;
    *(float4*)&Wl[r * 132 + c4 * 4] = *(const float4*)&W[r * DIM + c4 * 4];
  }

  const int rl  = t >> 7;
  const int j   = t & 127;
  const int wid = t >> 6;
  const float bj = bias[j];
  const int pairs = (R + 1) >> 1;

  for (int p = blockIdx.x; p < pairs; p += gridDim.x) {
    const int row = p * 2 + rl;
    const bool valid = row < R;
    __syncthreads();
    xl[rl * DIM + j] = valid ? X[(size_t)row * DIM + j] : 0.0f;
    __syncthreads();

    float acc = bj;
    #pragma unroll
    for (int i4 = 0; i4 < 32; ++i4) {
      float4 xv = *(const float4*)&xl[rl * DIM + i4 * 4];
      float4 wv = *(const float4*)&Wl[j * 132 + i4 * 4];
      acc = fmaf(xv.x, wv.x, acc);
      acc = fmaf(xv.y, wv.y, acc);
      acc = fmaf(xv.z, wv.z, acc);
      acc = fmaf(xv.w, wv.w, acc);
    }
    const float h = tanhf(acc);

    float s = h * h;
    #pragma unroll
    for (int o = 32; o > 0; o >>= 1) s += __shfl_xor(s, o);
    if ((t & 63) == 0) red[wid] = s;
    __syncthreads();
    const float norm2 = red[rl * 2] + red[rl * 2 + 1];
    const float norm  = sqrtf(norm2);
    const float scale = (norm > 0.9f) ? (0.9f / norm) : 1.0f;

    if (valid) {
      const float pv = h * scale;
      P[(size_t)row * DIM + j] = pv;
      if (Pbf) Pbf[(size_t)row * DIM + j] = f2bf(pv);
      if (j == 0) P2[row] = norm2 * scale * scale;
    }
  }
}

// ---------------------------------------------------------------------------
// Kernel 2: bf16-MFMA approx scoring + per-(query,split) top-16 (32-bit keys)
//   512 thr (8 waves), QB=64 queries, MB=128 tile; rank value = m2+2-2*dot
//   key = (f32bits & 0xFFFFE000) | local_idx(13b); exact rescore in K3.
// ---------------------------------------------------------------------------
template<bool USEBF>
__global__ __launch_bounds__(512, 4) void score_topk_k(
    const float* __restrict__ Pq,
    const float* __restrict__ Pm, const float* __restrict__ Pm2,
    const unsigned short* __restrict__ Pmbf,
    int N, unsigned* __restrict__ splitTop)
{
  __shared__ __align__(16) unsigned short Ml[MB * 128];  // 32 KB swizzled bf16
  __shared__ __align__(16) float dl[QB * 132];           // 33.8 KB rank values
  __shared__ float m2p2l[MB];

  const int t = threadIdx.x;
  const int lane = t & 63;
  const int w = t >> 6, wr = w >> 2, wc = w & 3;
  const int split = blockIdx.x;
  const int qbase = blockIdx.y * QB;
  const int mlo = (int)(((long long)split * N) / NSPLIT);
  const int mhi = (int)(((long long)(split + 1) * N) / NSPLIT);

  // persistent Q fragments (A operand): row = lane&15, k-chunk = (lane>>4)*8
  bf16x8 qf[2][4];
  #pragma unroll
  for (int s = 0; s < 2; ++s) {
    const int qrow = qbase + (wr * 2 + s) * 16 + (lane & 15);
    #pragma unroll
    for (int ks = 0; ks < 4; ++ks) {
      const float* src = &Pq[(size_t)qrow * DIM + ks * 32 + (lane >> 4) * 8];
      float4 lo = *(const float4*)src;
      float4 hi = *(const float4*)(src + 4);
      bf16x8 v;
      v[0] = (short)f2bf(lo.x); v[1] = (short)f2bf(lo.y);
      v[2] = (short)f2bf(lo.z); v[3] = (short)f2bf(lo.w);
      v[4] = (short)f2bf(hi.x); v[5] = (short)f2bf(hi.y);
      v[6] = (short)f2bf(hi.z); v[7] = (short)f2bf(hi.w);
      qf[s][ks] = v;
    }
  }

  // --- staging: load-early / write-late (T14). LDS swizzle: chunk ^= row&7
  uint4 sv[4];
  float m2s = 0.0f;

  auto stage_load = [&](int mbase) {
    if constexpr (USEBF) {
      #pragma unroll
      for (int p = 0; p < 4; ++p) {
        const int r = p * 32 + (t >> 4);
        const int c = t & 15;
        sv[p] = *(const uint4*)(Pmbf + (size_t)(mbase + r) * DIM + ((c ^ (r & 7)) << 3));
      }
    } else {
      const int r = t >> 2, qt = t & 3;
      const float* src = Pm + (size_t)(mbase + r) * DIM + qt * 32;
      #pragma unroll
      for (int u = 0; u < 4; ++u) {
        float4 a = *(const float4*)(src + u * 8);
        float4 b = *(const float4*)(src + u * 8 + 4);
        uint4 o;
        o.x = (unsigned)f2bf(a.x) | ((unsigned)f2bf(a.y) << 16);
        o.y = (unsigned)f2bf(a.z) | ((unsigned)f2bf(a.w) << 16);
        o.z = (unsigned)f2bf(b.x) | ((unsigned)f2bf(b.y) << 16);
        o.w = (unsigned)f2bf(b.z) | ((unsigned)f2bf(b.w) << 16);
        sv[u] = o;
      }
    }
    if (t < MB) {
      const int gr = mbase + t;
      m2s = (gr < mhi) ? (Pm2[gr] + 2.0f) : __int_as_float(0x7f800000);
    }
  };

  auto stage_write = [&]() {
    if constexpr (USEBF) {
      #pragma unroll
      for (int p = 0; p < 4; ++p) {
        const int r = p * 32 + (t >> 4);
        const int c = t & 15;
        *(uint4*)((char*)Ml + r * 256 + c * 16) = sv[p];
      }
    } else {
      const int r = t >> 2, qt = t & 3;
      char* base = (char*)Ml + r * 256;
      #pragma unroll
      for (int u = 0; u < 4; ++u)
        *(uint4*)(base + ((((qt * 4 + u) ^ (r & 7))) << 4)) = sv[u];
    }
    if (t < MB) m2p2l[t] = m2s;
  };

  stage_load(mlo);
  stage_write();
  __syncthreads();

  unsigned keys[KSEL];
  #pragma unroll
  for (int i = 0; i < KSEL; ++i) keys[i] = 0xFFFFFFFFu;
  unsigned wloose = 0xFFFFFFFFu;

  const int ntiles = (mhi - mlo + MB - 1) / MB;
  const int qi = t >> 3, c0 = t & 7;

  for (int tile = 0; tile < ntiles; ++tile) {
    const int mbase = mlo + tile * MB;

    // ---- Phase A: MFMA on Ml, rank values -> dl
    const int m0 = wc * 32 + (lane & 15);
    const float m2a = m2p2l[m0];
    const float m2b = m2p2l[m0 + 16];

    f32x4 acc[2][2];
    #pragma unroll
    for (int s = 0; s < 2; ++s)
      #pragma unroll
      for (int n = 0; n < 2; ++n) acc[s][n] = (f32x4){0.f, 0.f, 0.f, 0.f};

    #pragma unroll
    for (int ks = 0; ks < 4; ++ks) {
      #pragma unroll
      for (int n = 0; n < 2; ++n) {
        const int row = (wc * 2 + n) * 16 + (lane & 15);
        const int cb  = (ks * 64 + (lane >> 4) * 16) ^ ((row & 7) << 4);
        bf16x8 bfr = *(const bf16x8*)((const char*)Ml + row * 256 + cb);
        acc[0][n] = mfma16(qf[0][ks], bfr, acc[0][n]);
        acc[1][n] = mfma16(qf[1][ks], bfr, acc[1][n]);
      }
    }

    #pragma unroll
    for (int s = 0; s < 2; ++s) {
      const int qv = wr * 32 + s * 16 + ((lane >> 4) << 2);
      #pragma unroll
      for (int n = 0; n < 2; ++n) {
        const float m2v = n ? m2b : m2a;
        const int m = wc * 32 + n * 16 + (lane & 15);
        #pragma unroll
        for (int r = 0; r < 4; ++r)
          dl[(qv + r) * 132 + m] = fmaf(-2.0f, acc[s][n][r], m2v);
      }
    }
    __syncthreads();

    // ---- Phase B: issue next-tile loads; scan dl; write next tile to LDS
    const bool more = (tile + 1 < ntiles);
    if (more) stage_load(mbase + MB);

    const int lcb = (mbase - mlo) + c0 * 16;
    #pragma unroll
    for (int u = 0; u < 4; ++u) {
      const uint4 v = *(const uint4*)&dl[qi * 132 + c0 * 16 + u * 4];
      const unsigned be[4] = {v.x, v.y, v.z, v.w};
      #pragma unroll
      for (int e = 0; e < 4; ++e) {
        if (be[e] <= wloose) {               // unsigned bits test (vals > 0)
          unsigned c = (be[e] & KEYMASK) | (unsigned)(lcb + u * 4 + e);
          #pragma unroll
          for (int i = 0; i < KSEL; ++i) {   // branch-free sorted insert
            const unsigned lo = c < keys[i] ? c : keys[i];
            c = c < keys[i] ? keys[i] : c;
            keys[i] = lo;
          }
          wloose = keys[KSEL - 1] | IDXMASK;
        }
      }
    }

    if (more) stage_write();
    __syncthreads();
  }

  // merge 8 owners per query (sorted lists, shfl groups of 8), emit sorted 16
  for (int r = 0; r < KSEL; ++r) {
    unsigned g = keys[0], o;
    o = __shfl_xor(g, 1, 8); g = o < g ? o : g;
    o = __shfl_xor(g, 2, 8); g = o < g ? o : g;
    o = __shfl_xor(g, 4, 8); g = o < g ? o : g;
    if (keys[0] == g) {
      #pragma unroll
      for (int i = 0; i < KSEL - 1; ++i) keys[i] = keys[i + 1];
      keys[KSEL - 1] = 0xFFFFFFFFu;
    }
    if (c0 == 0)
      splitTop[((size_t)(qbase + qi) * NSPLIT + split) * KSEL + r] = g;
  }
}

// ---------------------------------------------------------------------------
// Kernel 3: merge 256 split candidates -> approx top-32 -> EXACT fp32 rescore
//           -> exact top-16, softmax weights, gather outcomes.
// ---------------------------------------------------------------------------
__global__ __launch_bounds__(256) void finalize_k(
    const unsigned* __restrict__ splitTop,
    const float* __restrict__ Pq, const float* __restrict__ Pq2,
    const float* __restrict__ Pm, const float* __restrict__ Pm2,
    const float* __restrict__ memOut, int N,
    float* __restrict__ outW, float* __restrict__ outO)
{
  const int q = blockIdx.x;
  const int t = threadIdx.x;
  __shared__ unsigned selKey[RESCORE];
  __shared__ int      selSrc[RESCORE];
  __shared__ unsigned long long keyx[RESCORE];
  __shared__ unsigned long long selB[KSEL];
  __shared__ float el[KSEL];

  // phase A: approx top-32 of 256 keys (wave 0; 4 keys per lane)
  if (t < 64) {
    unsigned k0 = splitTop[(size_t)q * 256 + t * 4 + 0];
    unsigned k1 = splitTop[(size_t)q * 256 + t * 4 + 1];
    unsigned k2 = splitTop[(size_t)q * 256 + t * 4 + 2];
    unsigned k3 = splitTop[(size_t)q * 256 + t * 4 + 3];
    for (int r = 0; r < RESCORE; ++r) {
      unsigned a01 = k0 < k1 ? k0 : k1;
      unsigned a23 = k2 < k3 ? k2 : k3;
      unsigned mymin = a01 < a23 ? a01 : a23;
      unsigned g = mymin, o;
      #pragma unroll
      for (int s = 1; s < 64; s <<= 1) { o = __shfl_xor(g, s); g = o < g ? o : g; }
      unsigned long long mask = __ballot(mymin == g);
      int fl = __ffsll((unsigned long long)mask) - 1;
      if (t == fl) {
        selKey[r] = g;
        if      (k0 == g) { k0 = 0xFFFFFFFFu; selSrc[r] = t * 4 + 0; }
        else if (k1 == g) { k1 = 0xFFFFFFFFu; selSrc[r] = t * 4 + 1; }
        else if (k2 == g) { k2 = 0xFFFFFFFFu; selSrc[r] = t * 4 + 2; }
        else              { k3 = 0xFFFFFFFFu; selSrc[r] = t * 4 + 3; }
      }
    }
  }
  __syncthreads();

  // phase B: exact fp32 rescore of 32 candidates, 8 threads each
  {
    const int g = t >> 3, e = t & 7;
    const int src = selSrc[g];
    const int split = src >> 4;
    const int gidx = (int)(((long long)split * N) / NSPLIT) +
                     (int)(selKey[g] & IDXMASK);
    const float4* qr = (const float4*)&Pq[(size_t)q * DIM];
    const float4* mr = (const float4*)&Pm[(size_t)gidx * DIM];
    float s = 0.f;
    #pragma unroll
    for (int u = 0; u < 4; ++u) {
      float4 a = qr[e * 4 + u], b = mr[e * 4 + u];
      s = fmaf(a.x, b.x, s); s = fmaf(a.y, b.y, s);
      s = fmaf(a.z, b.z, s); s = fmaf(a.w, b.w, s);
    }
    s += __shfl_xor(s, 1, 8);
    s += __shfl_xor(s, 2, 8);
    s += __shfl_xor(s, 4, 8);
    if (e == 0) {
      float d2 = (Pq2[q] + Pm2[gidx]) - 2.0f * s;
      float dist = sqrtf(fmaxf(d2, 1e-12f));
      keyx[g] = (((unsigned long long)__float_as_uint(dist)) << 32) | (unsigned)gidx;
    }
  }
  __syncthreads();

  // phase C: exact top-16 of the 32 (wave 0)
  if (t < 64) {
    unsigned long long kk = (t < RESCORE) ? keyx[t] : ~0ull;
    for (int r = 0; r < KSEL; ++r) {
      unsigned long long g = kk;
      #pragma unroll
      for (int o = 1; o < 64; o <<= 1) {
        unsigned long long s = __shfl_xor(g, o);
        g = (s < g) ? s : g;
      }
      if (kk == g) kk = ~0ull;
      if (t == 0) selB[r] = g;
    }
  }
  __syncthreads();

  if (t < KSEL) {
    const float d  = __uint_as_float((unsigned)(selB[t] >> 32));
    const float d0 = __uint_as_float((unsigned)(selB[0] >> 32));
    el[t] = expf(-(d / 0.1f) + (d0 / 0.1f));
  }
  __syncthreads();
  if (t < KSEL) {
    float sum = 0.f;
    #pragma unroll
    for (int i = 0; i < KSEL; ++i) sum += el[i];
    outW[(size_t)q * KSEL + t] = el[t] / sum;
  }

  for (int f4 = t; f4 < KSEL * 32; f4 += 256) {
    int r = f4 >> 5, c4 = f4 & 31;
    int idx = (int)(selB[r] & 0xffffffffu);
    *(float4*)&outO[((size_t)q * KSEL + r) * DIM + c4 * 4] =
        *(const float4*)&memOut[(size_t)idx * DIM + c4 * 4];
  }
}

// ---------------------------------------------------------------------------
extern "C" void kernel_launch(void* const* d_in, const int* in_sizes, int n_in,
                              void* d_out, int out_size, void* d_ws, size_t ws_size,
                              hipStream_t stream)
{
  const float* query   = (const float*)d_in[0];
  const float* W       = (const float*)d_in[1];
  const float* bias    = (const float*)d_in[2];
  const float* mem_emb = (const float*)d_in[3];
  const float* mem_out = (const float*)d_in[4];
  const int B = in_sizes[0] / DIM;   // 2048
  const int N = in_sizes[3] / DIM;   // 100000
  const int N_pad = ((N + MB + 15) / 16) * 16;   // covers last-split tile overrun

  // workspace: Pm fp32 | Pm2 | Pq | Pq2 | splitTop | [Pm bf16 if it fits]
  float* ws  = (float*)d_ws;
  float* Pm  = ws;
  float* Pm2 = Pm + (size_t)N_pad * DIM;
  float* Pq  = Pm2 + N_pad;
  float* Pq2 = Pq + (size_t)B * DIM;
  unsigned* splitTop = (unsigned*)(Pq2 + B);
  unsigned short* Pmbf = (unsigned short*)(splitTop + (size_t)B * NSPLIT * KSEL);
  const size_t need_bf = (size_t)((char*)(Pmbf + (size_t)N_pad * DIM) - (char*)d_ws);
  const bool usebf = ws_size >= need_bf;

  float* outW = (float*)d_out;
  float* outO = outW + (size_t)B * KSEL;

  // 1) Poincare transforms (fp32 exact basis; bf16 copy for scoring if room)
  poincare_k<<<dim3(1024), dim3(256), 0, stream>>>(mem_emb, N, W, bias, Pm, Pm2,
                                                   usebf ? Pmbf : nullptr);
  poincare_k<<<dim3(1024), dim3(256), 0, stream>>>(query, B, W, bias, Pq, Pq2,
                                                   nullptr);

  // 2) bf16-MFMA approx scoring + split top-16
  dim3 grid2(NSPLIT, B / QB);
  if (usebf)
    score_topk_k<true><<<grid2, dim3(512), 0, stream>>>(Pq, Pm, Pm2, Pmbf, N, splitTop);
  else
    score_topk_k<false><<<grid2, dim3(512), 0, stream>>>(Pq, Pm, Pm2, nullptr, N, splitTop);

  // 3) merge + exact rescore + softmax + gather
  finalize_k<<<dim3(B), dim3(256), 0, stream>>>(splitTop, Pq, Pq2, Pm, Pm2,
                                                mem_out, N, outW, outO);
}

// Round 4
// 438.598 us; speedup vs baseline: 6.2590x; 1.2412x over previous
//
#include <hip/hip_runtime.h>
#include <hip/hip_bf16.h>
#include <math.h>

#define DIM 128
#define QB 64
#define MB 128
#define NSPLIT 16
#define KSEL 16
#define RESCORE 32
#define IDXMASK 0x1FFFu
#define KEYMASK 0xFFFFE000u

using bf16x8 = __attribute__((ext_vector_type(8))) short;
using f32x4  = __attribute__((ext_vector_type(4))) float;

__device__ inline unsigned short f2bf(float f) {
  __hip_bfloat16 h = __float2bfloat16(f);   // RNE
  return __builtin_bit_cast(unsigned short, h);
}

__device__ inline f32x4 mfma16(bf16x8 a, bf16x8 b, f32x4 c) {
  return __builtin_amdgcn_mfma_f32_16x16x32_bf16(a, b, c, 0, 0, 0);
}

__device__ inline void gload_lds16(const void* g, void* l) {
  __builtin_amdgcn_global_load_lds(
      (const __attribute__((address_space(1))) void*)g,
      (__attribute__((address_space(3))) void*)l, 16, 0, 0);
}

// ---------------------------------------------------------------------------
// Kernel 1: Poincare transform  P = clip_ball(tanh(X @ W^T + b)), P2 = ||P||^2
//   128-row tile per block, 512 thr; thread = 4 rows x 8 cols register tile.
//   xl granule-swizzled (c ^ (r&7)) so 4-row-strided b128 reads spread banks.
// ---------------------------------------------------------------------------
__global__ __launch_bounds__(512) void poincare_k(
    const float* __restrict__ X, int R,
    const float* __restrict__ W, const float* __restrict__ bias,
    float* __restrict__ P, float* __restrict__ P2,
    unsigned short* __restrict__ Pbf)
{
  __shared__ float Wl[DIM * DIM];        // 64 KB  (linear; reads broadcast)
  __shared__ float xl[128 * DIM];        // 64 KB  (granule-swizzled)
  __shared__ float nrm[128 * 17];        // 8.5 KB partials [row][cg]
  __shared__ float norm2l[128];

  const int t  = threadIdx.x;
  const int cg = t >> 5;                 // 0..15  (8 cols each)
  const int rg = t & 31;                 // 0..31  (rows rg + 32v)
  const int rbase = blockIdx.x * 128;

  for (int i = t; i < DIM * 32; i += 512) {
    const int j = i >> 5, c = i & 31;
    *(float4*)&Wl[j * DIM + c * 4] = *(const float4*)&W[j * DIM + c * 4];
  }
  for (int i = t; i < 128 * 32; i += 512) {
    const int r = i >> 5, c = i & 31;
    float4 v = {0.f, 0.f, 0.f, 0.f};
    if (rbase + r < R) v = *(const float4*)&X[(size_t)(rbase + r) * DIM + c * 4];
    *(float4*)&xl[r * DIM + ((c ^ (r & 7)) << 2)] = v;
  }
  float bj[8];
  #pragma unroll
  for (int u = 0; u < 8; ++u) bj[u] = bias[cg * 8 + u];
  __syncthreads();

  float acc[4][8];
  #pragma unroll
  for (int v = 0; v < 4; ++v)
    #pragma unroll
    for (int u = 0; u < 8; ++u) acc[v][u] = bj[u];

  #pragma unroll 4
  for (int k4 = 0; k4 < 32; ++k4) {
    float4 xv[4], wv[8];
    #pragma unroll
    for (int v = 0; v < 4; ++v) {
      const int r = rg + 32 * v;
      xv[v] = *(const float4*)&xl[r * DIM + ((k4 ^ (r & 7)) << 2)];
    }
    #pragma unroll
    for (int u = 0; u < 8; ++u)
      wv[u] = *(const float4*)&Wl[(cg * 8 + u) * DIM + k4 * 4];
    #pragma unroll
    for (int v = 0; v < 4; ++v)
      #pragma unroll
      for (int u = 0; u < 8; ++u) {
        acc[v][u] = fmaf(xv[v].x, wv[u].x, acc[v][u]);
        acc[v][u] = fmaf(xv[v].y, wv[u].y, acc[v][u]);
        acc[v][u] = fmaf(xv[v].z, wv[u].z, acc[v][u]);
        acc[v][u] = fmaf(xv[v].w, wv[u].w, acc[v][u]);
      }
  }

  // tanh + per-(row,cg) partial norms
  #pragma unroll
  for (int v = 0; v < 4; ++v) {
    float pn = 0.f;
    #pragma unroll
    for (int u = 0; u < 8; ++u) {
      const float th = tanhf(acc[v][u]);
      acc[v][u] = th;
      pn = fmaf(th, th, pn);
    }
    nrm[(rg + 32 * v) * 17 + cg] = pn;
  }
  __syncthreads();
  if (t < 128) {
    float s = 0.f;
    #pragma unroll
    for (int c2 = 0; c2 < 16; ++c2) s += nrm[t * 17 + c2];
    norm2l[t] = s;
    if (rbase + t < R) {
      const float nm = sqrtf(s);
      const float sc = (nm > 0.9f) ? (0.9f / nm) : 1.0f;
      P2[rbase + t] = s * sc * sc;
    }
  }
  __syncthreads();

  #pragma unroll
  for (int v = 0; v < 4; ++v) {
    const int r = rg + 32 * v;
    const int row = rbase + r;
    if (row < R) {
      const float n2 = norm2l[r];
      const float nm = sqrtf(n2);
      const float sc = (nm > 0.9f) ? (0.9f / nm) : 1.0f;
      float o[8];
      #pragma unroll
      for (int u = 0; u < 8; ++u) o[u] = acc[v][u] * sc;
      *(float4*)&P[(size_t)row * DIM + cg * 8]     = make_float4(o[0], o[1], o[2], o[3]);
      *(float4*)&P[(size_t)row * DIM + cg * 8 + 4] = make_float4(o[4], o[5], o[6], o[7]);
      if (Pbf) {
        uint4 pb;
        pb.x = (unsigned)f2bf(o[0]) | ((unsigned)f2bf(o[1]) << 16);
        pb.y = (unsigned)f2bf(o[2]) | ((unsigned)f2bf(o[3]) << 16);
        pb.z = (unsigned)f2bf(o[4]) | ((unsigned)f2bf(o[5]) << 16);
        pb.w = (unsigned)f2bf(o[6]) | ((unsigned)f2bf(o[7]) << 16);
        *(uint4*)&Pbf[(size_t)row * DIM + cg * 8] = pb;
      }
    }
  }
}

// ---------------------------------------------------------------------------
// Kernel 2: bf16-MFMA approx scoring + per-(query,split) top-16 (32-bit keys)
//   USEBF path: direct global->LDS staging (global_load_lds, 16B), no reg
//   round-trip; pre-swizzled global source, linear LDS dest (m173 pattern).
// ---------------------------------------------------------------------------
template<bool USEBF>
__global__ __launch_bounds__(512, USEBF ? 4 : 2) void score_topk_k(
    const float* __restrict__ Pq,
    const float* __restrict__ Pm, const float* __restrict__ Pm2,
    const unsigned short* __restrict__ Pmbf,
    int N, unsigned* __restrict__ splitTop)
{
  __shared__ __align__(16) unsigned short Ml[MB * 128];  // 32 KB swizzled bf16
  __shared__ __align__(16) float dl[QB * 132];           // 33.8 KB rank values
  __shared__ float m2p2l[2][MB];

  const int t = threadIdx.x;
  const int lane = t & 63;
  const int w = t >> 6, wr = w >> 2, wc = w & 3;
  const int split = blockIdx.x;
  const int qbase = blockIdx.y * QB;
  const int mlo = (int)(((long long)split * N) / NSPLIT);
  const int mhi = (int)(((long long)(split + 1) * N) / NSPLIT);

  // persistent Q fragments (A operand): row = lane&15, k-chunk = (lane>>4)*8
  bf16x8 qf[2][4];
  #pragma unroll
  for (int s = 0; s < 2; ++s) {
    const int qrow = qbase + (wr * 2 + s) * 16 + (lane & 15);
    #pragma unroll
    for (int ks = 0; ks < 4; ++ks) {
      const float* src = &Pq[(size_t)qrow * DIM + ks * 32 + (lane >> 4) * 8];
      float4 lo = *(const float4*)src;
      float4 hi = *(const float4*)(src + 4);
      bf16x8 v;
      v[0] = (short)f2bf(lo.x); v[1] = (short)f2bf(lo.y);
      v[2] = (short)f2bf(lo.z); v[3] = (short)f2bf(lo.w);
      v[4] = (short)f2bf(hi.x); v[5] = (short)f2bf(hi.y);
      v[6] = (short)f2bf(hi.z); v[7] = (short)f2bf(hi.w);
      qf[s][ks] = v;
    }
  }

  // ---- staging helpers -----------------------------------------------------
  // USEBF: wave w stages rows w*16..w*16+15; per issue i: rows w*16+i*4+(l>>4),
  // chunk c=l&15, global col pre-swizzled (c ^ (r&7)); LDS dest linear.
  uint4 sv[4];                                   // !USEBF fallback only
  auto stage_issue = [&](int mbase) {
    if constexpr (USEBF) {
      #pragma unroll
      for (int i = 0; i < 4; ++i) {
        const int r = w * 16 + i * 4 + (lane >> 4);
        const int c = lane & 15;
        const unsigned short* src =
            Pmbf + (size_t)(mbase + r) * DIM + ((c ^ (r & 7)) << 3);
        gload_lds16(src, &Ml[(w * 16 + i * 4) * DIM]);
      }
    } else {
      const int r = t >> 2, qt = t & 3;
      const float* src = Pm + (size_t)(mbase + r) * DIM + qt * 32;
      #pragma unroll
      for (int u = 0; u < 4; ++u) {
        float4 a = *(const float4*)(src + u * 8);
        float4 b = *(const float4*)(src + u * 8 + 4);
        uint4 o;
        o.x = (unsigned)f2bf(a.x) | ((unsigned)f2bf(a.y) << 16);
        o.y = (unsigned)f2bf(a.z) | ((unsigned)f2bf(a.w) << 16);
        o.z = (unsigned)f2bf(b.x) | ((unsigned)f2bf(b.y) << 16);
        o.w = (unsigned)f2bf(b.z) | ((unsigned)f2bf(b.w) << 16);
        sv[u] = o;
      }
    }
  };
  auto stage_write_fallback = [&]() {
    if constexpr (!USEBF) {
      const int r = t >> 2, qt = t & 3;
      char* base = (char*)Ml + r * 256;
      #pragma unroll
      for (int u = 0; u < 4; ++u)
        *(uint4*)(base + (((qt * 4 + u) ^ (r & 7)) << 4)) = sv[u];
    }
  };

  // prologue: stage tile 0 + its m2
  stage_issue(mlo);
  {
    float m2n = __int_as_float(0x7f800000);
    if (t < MB) {
      const int gr = mlo + t;
      if (gr < mhi) m2n = Pm2[gr] + 2.0f;
    }
    stage_write_fallback();
    if (t < MB) m2p2l[0][t] = m2n;
  }
  __syncthreads();

  unsigned keys[KSEL];
  #pragma unroll
  for (int i = 0; i < KSEL; ++i) keys[i] = 0xFFFFFFFFu;
  unsigned wloose = 0xFFFFFFFFu;

  const int ntiles = (mhi - mlo + MB - 1) / MB;
  const int qi = t >> 3, c0 = t & 7;

  for (int tile = 0; tile < ntiles; ++tile) {
    const int mbase = mlo + tile * MB;
    const int cur = tile & 1;

    // ---- Phase A: MFMA on Ml, rank values (m2+2-2*dot) -> dl
    const int m0 = wc * 32 + (lane & 15);
    const float m2a = m2p2l[cur][m0];
    const float m2b = m2p2l[cur][m0 + 16];

    f32x4 acc[2][2];
    #pragma unroll
    for (int s = 0; s < 2; ++s)
      #pragma unroll
      for (int n = 0; n < 2; ++n) acc[s][n] = (f32x4){0.f, 0.f, 0.f, 0.f};

    __builtin_amdgcn_s_setprio(1);
    #pragma unroll
    for (int ks = 0; ks < 4; ++ks) {
      #pragma unroll
      for (int n = 0; n < 2; ++n) {
        const int row = (wc * 2 + n) * 16 + (lane & 15);
        const int cb  = (ks * 64 + (lane >> 4) * 16) ^ ((row & 7) << 4);
        bf16x8 bfr = *(const bf16x8*)((const char*)Ml + row * 256 + cb);
        acc[0][n] = mfma16(qf[0][ks], bfr, acc[0][n]);
        acc[1][n] = mfma16(qf[1][ks], bfr, acc[1][n]);
      }
    }
    __builtin_amdgcn_s_setprio(0);

    #pragma unroll
    for (int s = 0; s < 2; ++s) {
      const int qv = wr * 32 + s * 16 + ((lane >> 4) << 2);
      #pragma unroll
      for (int n = 0; n < 2; ++n) {
        const float m2v = n ? m2b : m2a;
        const int m = wc * 32 + n * 16 + (lane & 15);
        #pragma unroll
        for (int r = 0; r < 4; ++r)
          dl[(qv + r) * 132 + m] = fmaf(-2.0f, acc[s][n][r], m2v);
      }
    }
    __syncthreads();   // all waves done reading Ml + dl complete

    // ---- Phase B: issue next-tile loads into Ml (async), scan dl meanwhile
    const bool more = (tile + 1 < ntiles);
    float m2n = __int_as_float(0x7f800000);
    if (more) {
      stage_issue(mbase + MB);
      if (t < MB) {
        const int gr = mbase + MB + t;
        if (gr < mhi) m2n = Pm2[gr] + 2.0f;
      }
    }

    const int lcb = (mbase - mlo) + c0 * 16;
    #pragma unroll
    for (int u = 0; u < 4; ++u) {
      const uint4 v = *(const uint4*)&dl[qi * 132 + c0 * 16 + u * 4];
      const unsigned be[4] = {v.x, v.y, v.z, v.w};
      #pragma unroll
      for (int e = 0; e < 4; ++e) {
        if (be[e] <= wloose) {               // unsigned bits test (vals >= 0)
          unsigned c = (be[e] & KEYMASK) | (unsigned)(lcb + u * 4 + e);
          #pragma unroll
          for (int i = 0; i < KSEL; ++i) {   // branch-free sorted insert
            const unsigned lo = c < keys[i] ? c : keys[i];
            c = c < keys[i] ? keys[i] : c;
            keys[i] = lo;
          }
          wloose = keys[KSEL - 1] | IDXMASK;
        }
      }
    }

    if (more) {
      stage_write_fallback();
      if (t < MB) m2p2l[cur ^ 1][t] = m2n;
    }
    __syncthreads();   // drains vmcnt (global_load_lds) + lds writes
  }

  // merge 8 owners per query (sorted lists, shfl groups of 8), emit sorted 16
  for (int r = 0; r < KSEL; ++r) {
    unsigned g = keys[0], o;
    o = __shfl_xor(g, 1, 8); g = o < g ? o : g;
    o = __shfl_xor(g, 2, 8); g = o < g ? o : g;
    o = __shfl_xor(g, 4, 8); g = o < g ? o : g;
    if (keys[0] == g) {
      #pragma unroll
      for (int i = 0; i < KSEL - 1; ++i) keys[i] = keys[i + 1];
      keys[KSEL - 1] = 0xFFFFFFFFu;
    }
    if (c0 == 0)
      splitTop[((size_t)(qbase + qi) * NSPLIT + split) * KSEL + r] = g;
  }
}

// ---------------------------------------------------------------------------
// Kernel 3: merge 256 split candidates -> approx top-32 -> EXACT fp32 rescore
//           -> exact top-16, softmax weights, gather outcomes.
// ---------------------------------------------------------------------------
__global__ __launch_bounds__(256) void finalize_k(
    const unsigned* __restrict__ splitTop,
    const float* __restrict__ Pq, const float* __restrict__ Pq2,
    const float* __restrict__ Pm, const float* __restrict__ Pm2,
    const float* __restrict__ memOut, int N,
    float* __restrict__ outW, float* __restrict__ outO)
{
  const int q = blockIdx.x;
  const int t = threadIdx.x;
  __shared__ unsigned selKey[RESCORE];
  __shared__ int      selSrc[RESCORE];
  __shared__ unsigned long long keyx[RESCORE];
  __shared__ unsigned long long selB[KSEL];
  __shared__ float el[KSEL];

  // phase A: approx top-32 of 256 keys (wave 0; 4 keys per lane)
  if (t < 64) {
    unsigned k0 = splitTop[(size_t)q * 256 + t * 4 + 0];
    unsigned k1 = splitTop[(size_t)q * 256 + t * 4 + 1];
    unsigned k2 = splitTop[(size_t)q * 256 + t * 4 + 2];
    unsigned k3 = splitTop[(size_t)q * 256 + t * 4 + 3];
    for (int r = 0; r < RESCORE; ++r) {
      unsigned a01 = k0 < k1 ? k0 : k1;
      unsigned a23 = k2 < k3 ? k2 : k3;
      unsigned mymin = a01 < a23 ? a01 : a23;
      unsigned g = mymin, o;
      #pragma unroll
      for (int s = 1; s < 64; s <<= 1) { o = __shfl_xor(g, s); g = o < g ? o : g; }
      unsigned long long mask = __ballot(mymin == g);
      int fl = __ffsll((unsigned long long)mask) - 1;
      if (t == fl) {
        selKey[r] = g;
        if      (k0 == g) { k0 = 0xFFFFFFFFu; selSrc[r] = t * 4 + 0; }
        else if (k1 == g) { k1 = 0xFFFFFFFFu; selSrc[r] = t * 4 + 1; }
        else if (k2 == g) { k2 = 0xFFFFFFFFu; selSrc[r] = t * 4 + 2; }
        else              { k3 = 0xFFFFFFFFu; selSrc[r] = t * 4 + 3; }
      }
    }
  }
  __syncthreads();

  // phase B: exact fp32 rescore of 32 candidates, 8 threads each
  {
    const int g = t >> 3, e = t & 7;
    const int src = selSrc[g];
    const int split = src >> 4;
    const int gidx = (int)(((long long)split * N) / NSPLIT) +
                     (int)(selKey[g] & IDXMASK);
    const float4* qr = (const float4*)&Pq[(size_t)q * DIM];
    const float4* mr = (const float4*)&Pm[(size_t)gidx * DIM];
    float s = 0.f;
    #pragma unroll
    for (int u = 0; u < 4; ++u) {
      float4 a = qr[e * 4 + u], b = mr[e * 4 + u];
      s = fmaf(a.x, b.x, s); s = fmaf(a.y, b.y, s);
      s = fmaf(a.z, b.z, s); s = fmaf(a.w, b.w, s);
    }
    s += __shfl_xor(s, 1, 8);
    s += __shfl_xor(s, 2, 8);
    s += __shfl_xor(s, 4, 8);
    if (e == 0) {
      float d2 = (Pq2[q] + Pm2[gidx]) - 2.0f * s;
      float dist = sqrtf(fmaxf(d2, 1e-12f));
      keyx[g] = (((unsigned long long)__float_as_uint(dist)) << 32) | (unsigned)gidx;
    }
  }
  __syncthreads();

  // phase C: exact top-16 of the 32 (wave 0)
  if (t < 64) {
    unsigned long long kk = (t < RESCORE) ? keyx[t] : ~0ull;
    for (int r = 0; r < KSEL; ++r) {
      unsigned long long g = kk;
      #pragma unroll
      for (int o = 1; o < 64; o <<= 1) {
        unsigned long long s = __shfl_xor(g, o);
        g = (s < g) ? s : g;
      }
      if (kk == g) kk = ~0ull;
      if (t == 0) selB[r] = g;
    }
  }
  __syncthreads();

  if (t < KSEL) {
    const float d  = __uint_as_float((unsigned)(selB[t] >> 32));
    const float d0 = __uint_as_float((unsigned)(selB[0] >> 32));
    el[t] = expf(-(d / 0.1f) + (d0 / 0.1f));
  }
  __syncthreads();
  if (t < KSEL) {
    float sum = 0.f;
    #pragma unroll
    for (int i = 0; i < KSEL; ++i) sum += el[i];
    outW[(size_t)q * KSEL + t] = el[t] / sum;
  }

  for (int f4 = t; f4 < KSEL * 32; f4 += 256) {
    int r = f4 >> 5, c4 = f4 & 31;
    int idx = (int)(selB[r] & 0xffffffffu);
    *(float4*)&outO[((size_t)q * KSEL + r) * DIM + c4 * 4] =
        *(const float4*)&memOut[(size_t)idx * DIM + c4 * 4];
  }
}

// ---------------------------------------------------------------------------
extern "C" void kernel_launch(void* const* d_in, const int* in_sizes, int n_in,
                              void* d_out, int out_size, void* d_ws, size_t ws_size,
                              hipStream_t stream)
{
  const float* query   = (const float*)d_in[0];
  const float* W       = (const float*)d_in[1];
  const float* bias    = (const float*)d_in[2];
  const float* mem_emb = (const float*)d_in[3];
  const float* mem_out = (const float*)d_in[4];
  const int B = in_sizes[0] / DIM;   // 2048
  const int N = in_sizes[3] / DIM;   // 100000
  const int N_pad = ((N + MB + 15) / 16) * 16;   // covers last-split tile overrun

  // workspace: Pm fp32 | Pm2 | Pq | Pq2 | splitTop | [Pm bf16 if it fits]
  float* ws  = (float*)d_ws;
  float* Pm  = ws;
  float* Pm2 = Pm + (size_t)N_pad * DIM;
  float* Pq  = Pm2 + N_pad;
  float* Pq2 = Pq + (size_t)B * DIM;
  unsigned* splitTop = (unsigned*)(Pq2 + B);
  unsigned short* Pmbf = (unsigned short*)(splitTop + (size_t)B * NSPLIT * KSEL);
  const size_t need_bf = (size_t)((char*)(Pmbf + (size_t)N_pad * DIM) - (char*)d_ws);
  const bool usebf = ws_size >= need_bf;

  float* outW = (float*)d_out;
  float* outO = outW + (size_t)B * KSEL;

  // 1) Poincare transforms (fp32 exact basis; bf16 copy for scoring if room)
  poincare_k<<<dim3((N + 127) / 128), dim3(512), 0, stream>>>(
      mem_emb, N, W, bias, Pm, Pm2, usebf ? Pmbf : nullptr);
  poincare_k<<<dim3((B + 127) / 128), dim3(512), 0, stream>>>(
      query, B, W, bias, Pq, Pq2, nullptr);

  // 2) bf16-MFMA approx scoring + split top-16
  dim3 grid2(NSPLIT, B / QB);
  if (usebf)
    score_topk_k<true><<<grid2, dim3(512), 0, stream>>>(Pq, Pm, Pm2, Pmbf, N, splitTop);
  else
    score_topk_k<false><<<grid2, dim3(512), 0, stream>>>(Pq, Pm, Pm2, nullptr, N, splitTop);

  // 3) merge + exact rescore + softmax + gather
  finalize_k<<<dim3(B), dim3(256), 0, stream>>>(splitTop, Pq, Pq2, Pm, Pm2,
                                                mem_out, N, outW, outO);
}

// Round 5
// 264.792 us; speedup vs baseline: 10.3673x; 1.6564x over previous
//
#include <hip/hip_runtime.h>
#include <hip/hip_bf16.h>
#include <math.h>

#define DIM 128
#define QB 64
#define MB 128
#define NSPLIT 16
#define KSEL 16
#define KOWN 6
#define RESCORE 32
#define IDXMASK 0x1FFFu
#define KEYMASK 0xFFFFE000u

using bf16x8 = __attribute__((ext_vector_type(8))) short;
using f32x4  = __attribute__((ext_vector_type(4))) float;

__device__ inline unsigned short f2bf(float f) {
  __hip_bfloat16 h = __float2bfloat16(f);   // RNE
  return __builtin_bit_cast(unsigned short, h);
}

__device__ inline f32x4 mfma16(bf16x8 a, bf16x8 b, f32x4 c) {
  return __builtin_amdgcn_mfma_f32_16x16x32_bf16(a, b, c, 0, 0, 0);
}

__device__ inline void gload_lds16(const void* g, void* l) {
  __builtin_amdgcn_global_load_lds(
      (const __attribute__((address_space(1))) void*)g,
      (__attribute__((address_space(3))) void*)l, 16, 0, 0);
}

// ---------------------------------------------------------------------------
// Kernel 1: Poincare transform  P = clip_ball(tanh(X @ W^T + b)), P2 = ||P||^2
//   512 thr; thread = 4 rows (rg + 32v) x 8 cols (cg*8+u).
//   X read straight from global (broadcast-friendly: 16 lanes dup per row).
//   Wl swizzled (col ^ (j>>3)&7) so the 16 distinct W-rows/wave spread banks.
// ---------------------------------------------------------------------------
__global__ __launch_bounds__(512) void poincare_k(
    const float* __restrict__ X, int R,
    const float* __restrict__ W, const float* __restrict__ bias,
    float* __restrict__ P, float* __restrict__ P2,
    unsigned short* __restrict__ Pbf)
{
  __shared__ float Wl[DIM * DIM];        // 64 KB, swizzled
  __shared__ float nrm[128 * 17];        // 8.5 KB partials [row][cg]
  __shared__ float norm2l[128];

  const int t  = threadIdx.x;
  const int cg = t & 15;                 // 0..15 (8 cols each)
  const int rg = t >> 4;                 // 0..31 (rows rg + 32v)
  const int rbase = blockIdx.x * 128;

  for (int i = t; i < DIM * 32; i += 512) {
    const int j = i >> 5, c = i & 31;
    const float4 v = *(const float4*)&W[j * DIM + c * 4];
    *(float4*)&Wl[j * DIM + ((c ^ ((j >> 3) & 7)) << 2)] = v;
  }
  float bj[8];
  #pragma unroll
  for (int u = 0; u < 8; ++u) bj[u] = bias[cg * 8 + u];

  const float* xr[4];
  #pragma unroll
  for (int v = 0; v < 4; ++v) {
    int row = rbase + rg + 32 * v;
    if (row > R - 1) row = R - 1;        // clamp; invalid rows never stored
    xr[v] = X + (size_t)row * DIM;
  }
  __syncthreads();

  float acc[4][8];
  #pragma unroll
  for (int v = 0; v < 4; ++v)
    #pragma unroll
    for (int u = 0; u < 8; ++u) acc[v][u] = bj[u];

  #pragma unroll 2
  for (int k4 = 0; k4 < 32; ++k4) {
    float4 xv[4], wv[8];
    #pragma unroll
    for (int v = 0; v < 4; ++v) xv[v] = *(const float4*)&xr[v][k4 * 4];
    #pragma unroll
    for (int u = 0; u < 8; ++u) {
      const int j = cg * 8 + u;
      wv[u] = *(const float4*)&Wl[j * DIM + ((k4 ^ ((j >> 3) & 7)) << 2)];
    }
    #pragma unroll
    for (int v = 0; v < 4; ++v)
      #pragma unroll
      for (int u = 0; u < 8; ++u) {
        acc[v][u] = fmaf(xv[v].x, wv[u].x, acc[v][u]);
        acc[v][u] = fmaf(xv[v].y, wv[u].y, acc[v][u]);
        acc[v][u] = fmaf(xv[v].z, wv[u].z, acc[v][u]);
        acc[v][u] = fmaf(xv[v].w, wv[u].w, acc[v][u]);
      }
  }

  // tanh + per-(row,cg) partial norms
  #pragma unroll
  for (int v = 0; v < 4; ++v) {
    float pn = 0.f;
    #pragma unroll
    for (int u = 0; u < 8; ++u) {
      const float th = tanhf(acc[v][u]);
      acc[v][u] = th;
      pn = fmaf(th, th, pn);
    }
    nrm[(rg + 32 * v) * 17 + cg] = pn;
  }
  __syncthreads();
  if (t < 128) {
    float s = 0.f;
    #pragma unroll
    for (int c2 = 0; c2 < 16; ++c2) s += nrm[t * 17 + c2];
    norm2l[t] = s;
    if (rbase + t < R) {
      const float nm = sqrtf(s);
      const float sc = (nm > 0.9f) ? (0.9f / nm) : 1.0f;
      P2[rbase + t] = s * sc * sc;
    }
  }
  __syncthreads();

  #pragma unroll
  for (int v = 0; v < 4; ++v) {
    const int r = rg + 32 * v;
    const int row = rbase + r;
    if (row < R) {
      const float n2 = norm2l[r];
      const float nm = sqrtf(n2);
      const float sc = (nm > 0.9f) ? (0.9f / nm) : 1.0f;
      float o[8];
      #pragma unroll
      for (int u = 0; u < 8; ++u) o[u] = acc[v][u] * sc;
      *(float4*)&P[(size_t)row * DIM + cg * 8]     = make_float4(o[0], o[1], o[2], o[3]);
      *(float4*)&P[(size_t)row * DIM + cg * 8 + 4] = make_float4(o[4], o[5], o[6], o[7]);
      if (Pbf) {
        uint4 pb;
        pb.x = (unsigned)f2bf(o[0]) | ((unsigned)f2bf(o[1]) << 16);
        pb.y = (unsigned)f2bf(o[2]) | ((unsigned)f2bf(o[3]) << 16);
        pb.z = (unsigned)f2bf(o[4]) | ((unsigned)f2bf(o[5]) << 16);
        pb.w = (unsigned)f2bf(o[6]) | ((unsigned)f2bf(o[7]) << 16);
        *(uint4*)&Pbf[(size_t)row * DIM + cg * 8] = pb;
      }
    }
  }
}

// ---------------------------------------------------------------------------
// Kernel 2: bf16-MFMA approx scoring + per-(query,split) top-16 (32-bit keys)
//   Selection: BRANCH-FREE sorted-6 insert per owner stream (no divergence),
//   8 owners/query merged at the end into the emitted top-16.
// ---------------------------------------------------------------------------
template<bool USEBF>
__global__ __launch_bounds__(512, USEBF ? 4 : 2) void score_topk_k(
    const float* __restrict__ Pq,
    const float* __restrict__ Pm, const float* __restrict__ Pm2,
    const unsigned short* __restrict__ Pmbf,
    int N, unsigned* __restrict__ splitTop)
{
  __shared__ __align__(16) unsigned short Ml[MB * 128];  // 32 KB swizzled bf16
  __shared__ __align__(16) float dl[QB * 132];           // 33.8 KB rank values
  __shared__ float m2p2l[2][MB];

  const int t = threadIdx.x;
  const int lane = t & 63;
  const int w = t >> 6, wr = w >> 2, wc = w & 3;
  const int split = blockIdx.x;
  const int qbase = blockIdx.y * QB;
  const int mlo = (int)(((long long)split * N) / NSPLIT);
  const int mhi = (int)(((long long)(split + 1) * N) / NSPLIT);

  // persistent Q fragments (A operand): row = lane&15, k-chunk = (lane>>4)*8
  bf16x8 qf[2][4];
  #pragma unroll
  for (int s = 0; s < 2; ++s) {
    const int qrow = qbase + (wr * 2 + s) * 16 + (lane & 15);
    #pragma unroll
    for (int ks = 0; ks < 4; ++ks) {
      const float* src = &Pq[(size_t)qrow * DIM + ks * 32 + (lane >> 4) * 8];
      float4 lo = *(const float4*)src;
      float4 hi = *(const float4*)(src + 4);
      bf16x8 v;
      v[0] = (short)f2bf(lo.x); v[1] = (short)f2bf(lo.y);
      v[2] = (short)f2bf(lo.z); v[3] = (short)f2bf(lo.w);
      v[4] = (short)f2bf(hi.x); v[5] = (short)f2bf(hi.y);
      v[6] = (short)f2bf(hi.z); v[7] = (short)f2bf(hi.w);
      qf[s][ks] = v;
    }
  }

  // ---- staging helpers -----------------------------------------------------
  uint4 sv[4];                                   // !USEBF fallback only
  auto stage_issue = [&](int mbase) {
    if constexpr (USEBF) {
      #pragma unroll
      for (int i = 0; i < 4; ++i) {
        const int r = w * 16 + i * 4 + (lane >> 4);
        const int c = lane & 15;
        const unsigned short* src =
            Pmbf + (size_t)(mbase + r) * DIM + ((c ^ (r & 7)) << 3);
        gload_lds16(src, &Ml[(w * 16 + i * 4) * DIM]);
      }
    } else {
      const int r = t >> 2, qt = t & 3;
      const float* src = Pm + (size_t)(mbase + r) * DIM + qt * 32;
      #pragma unroll
      for (int u = 0; u < 4; ++u) {
        float4 a = *(const float4*)(src + u * 8);
        float4 b = *(const float4*)(src + u * 8 + 4);
        uint4 o;
        o.x = (unsigned)f2bf(a.x) | ((unsigned)f2bf(a.y) << 16);
        o.y = (unsigned)f2bf(a.z) | ((unsigned)f2bf(a.w) << 16);
        o.z = (unsigned)f2bf(b.x) | ((unsigned)f2bf(b.y) << 16);
        o.w = (unsigned)f2bf(b.z) | ((unsigned)f2bf(b.w) << 16);
        sv[u] = o;
      }
    }
  };
  auto stage_write_fallback = [&]() {
    if constexpr (!USEBF) {
      const int r = t >> 2, qt = t & 3;
      char* base = (char*)Ml + r * 256;
      #pragma unroll
      for (int u = 0; u < 4; ++u)
        *(uint4*)(base + (((qt * 4 + u) ^ (r & 7)) << 4)) = sv[u];
    }
  };

  // prologue: stage tile 0 + its m2
  stage_issue(mlo);
  {
    float m2n = __int_as_float(0x7f800000);
    if (t < MB) {
      const int gr = mlo + t;
      if (gr < mhi) m2n = Pm2[gr] + 2.0f;
    }
    stage_write_fallback();
    if (t < MB) m2p2l[0][t] = m2n;
  }
  __syncthreads();

  unsigned keys[KOWN];
  #pragma unroll
  for (int i = 0; i < KOWN; ++i) keys[i] = 0xFFFFFFFFu;

  const int ntiles = (mhi - mlo + MB - 1) / MB;
  const int qi = t >> 3, c0 = t & 7;

  for (int tile = 0; tile < ntiles; ++tile) {
    const int mbase = mlo + tile * MB;
    const int cur = tile & 1;

    // ---- Phase A: MFMA on Ml, rank values (m2+2-2*dot) -> dl
    const int m0 = wc * 32 + (lane & 15);
    const float m2a = m2p2l[cur][m0];
    const float m2b = m2p2l[cur][m0 + 16];

    f32x4 acc[2][2];
    #pragma unroll
    for (int s = 0; s < 2; ++s)
      #pragma unroll
      for (int n = 0; n < 2; ++n) acc[s][n] = (f32x4){0.f, 0.f, 0.f, 0.f};

    __builtin_amdgcn_s_setprio(1);
    #pragma unroll
    for (int ks = 0; ks < 4; ++ks) {
      #pragma unroll
      for (int n = 0; n < 2; ++n) {
        const int row = (wc * 2 + n) * 16 + (lane & 15);
        const int cb  = (ks * 64 + (lane >> 4) * 16) ^ ((row & 7) << 4);
        bf16x8 bfr = *(const bf16x8*)((const char*)Ml + row * 256 + cb);
        acc[0][n] = mfma16(qf[0][ks], bfr, acc[0][n]);
        acc[1][n] = mfma16(qf[1][ks], bfr, acc[1][n]);
      }
    }
    __builtin_amdgcn_s_setprio(0);

    #pragma unroll
    for (int s = 0; s < 2; ++s) {
      const int qv = wr * 32 + s * 16 + ((lane >> 4) << 2);
      #pragma unroll
      for (int n = 0; n < 2; ++n) {
        const float m2v = n ? m2b : m2a;
        const int m = wc * 32 + n * 16 + (lane & 15);
        #pragma unroll
        for (int r = 0; r < 4; ++r)
          dl[(qv + r) * 132 + m] = fmaf(-2.0f, acc[s][n][r], m2v);
      }
    }
    __syncthreads();   // all waves done reading Ml + dl complete

    // ---- Phase B: issue next-tile loads into Ml (async); scan dl meanwhile
    const bool more = (tile + 1 < ntiles);
    float m2n = __int_as_float(0x7f800000);
    if (more) {
      stage_issue(mbase + MB);
      if (t < MB) {
        const int gr = mbase + MB + t;
        if (gr < mhi) m2n = Pm2[gr] + 2.0f;
      }
    }

    // branch-free sorted-6 insert; 16 candidates/thread, no divergence
    const int lcb = (mbase - mlo) + c0 * 16;
    #pragma unroll
    for (int u = 0; u < 4; ++u) {
      const uint4 v = *(const uint4*)&dl[qi * 132 + c0 * 16 + u * 4];
      const unsigned be[4] = {v.x, v.y, v.z, v.w};
      #pragma unroll
      for (int e = 0; e < 4; ++e) {
        unsigned c = (be[e] & KEYMASK) | (unsigned)(lcb + u * 4 + e);
        #pragma unroll
        for (int i = 0; i < KOWN; ++i) {
          const unsigned lo = c < keys[i] ? c : keys[i];
          c = c < keys[i] ? keys[i] : c;
          keys[i] = lo;
        }
      }
    }

    if (more) {
      stage_write_fallback();
      if (t < MB) m2p2l[cur ^ 1][t] = m2n;
    }
    __syncthreads();   // drains vmcnt (global_load_lds) + lds writes
  }

  // merge 8 owners x sorted-6 per query (shfl groups of 8), emit sorted 16
  for (int r = 0; r < KSEL; ++r) {
    unsigned g = keys[0], o;
    o = __shfl_xor(g, 1, 8); g = o < g ? o : g;
    o = __shfl_xor(g, 2, 8); g = o < g ? o : g;
    o = __shfl_xor(g, 4, 8); g = o < g ? o : g;
    if (keys[0] == g) {
      #pragma unroll
      for (int i = 0; i < KOWN - 1; ++i) keys[i] = keys[i + 1];
      keys[KOWN - 1] = 0xFFFFFFFFu;
    }
    if (c0 == 0)
      splitTop[((size_t)(qbase + qi) * NSPLIT + split) * KSEL + r] = g;
  }
}

// ---------------------------------------------------------------------------
// Kernel 3: merge 256 split candidates -> approx top-32 -> EXACT fp32 rescore
//           -> exact top-16, softmax weights, gather outcomes.
// ---------------------------------------------------------------------------
__global__ __launch_bounds__(256) void finalize_k(
    const unsigned* __restrict__ splitTop,
    const float* __restrict__ Pq, const float* __restrict__ Pq2,
    const float* __restrict__ Pm, const float* __restrict__ Pm2,
    const float* __restrict__ memOut, int N,
    float* __restrict__ outW, float* __restrict__ outO)
{
  const int q = blockIdx.x;
  const int t = threadIdx.x;
  __shared__ unsigned selKey[RESCORE];
  __shared__ int      selSrc[RESCORE];
  __shared__ unsigned long long keyx[RESCORE];
  __shared__ unsigned long long selB[KSEL];
  __shared__ float el[KSEL];

  // phase A: approx top-32 of 256 keys (wave 0; 4 keys per lane)
  if (t < 64) {
    unsigned k0 = splitTop[(size_t)q * 256 + t * 4 + 0];
    unsigned k1 = splitTop[(size_t)q * 256 + t * 4 + 1];
    unsigned k2 = splitTop[(size_t)q * 256 + t * 4 + 2];
    unsigned k3 = splitTop[(size_t)q * 256 + t * 4 + 3];
    for (int r = 0; r < RESCORE; ++r) {
      unsigned a01 = k0 < k1 ? k0 : k1;
      unsigned a23 = k2 < k3 ? k2 : k3;
      unsigned mymin = a01 < a23 ? a01 : a23;
      unsigned g = mymin, o;
      #pragma unroll
      for (int s = 1; s < 64; s <<= 1) { o = __shfl_xor(g, s); g = o < g ? o : g; }
      unsigned long long mask = __ballot(mymin == g);
      int fl = __ffsll((unsigned long long)mask) - 1;
      if (t == fl) {
        selKey[r] = g;
        if      (k0 == g) { k0 = 0xFFFFFFFFu; selSrc[r] = t * 4 + 0; }
        else if (k1 == g) { k1 = 0xFFFFFFFFu; selSrc[r] = t * 4 + 1; }
        else if (k2 == g) { k2 = 0xFFFFFFFFu; selSrc[r] = t * 4 + 2; }
        else              { k3 = 0xFFFFFFFFu; selSrc[r] = t * 4 + 3; }
      }
    }
  }
  __syncthreads();

  // phase B: exact fp32 rescore of 32 candidates, 8 threads each
  {
    const int g = t >> 3, e = t & 7;
    const int src = selSrc[g];
    const int split = src >> 4;
    const int gidx = (int)(((long long)split * N) / NSPLIT) +
                     (int)(selKey[g] & IDXMASK);
    const float4* qr = (const float4*)&Pq[(size_t)q * DIM];
    const float4* mr = (const float4*)&Pm[(size_t)gidx * DIM];
    float s = 0.f;
    #pragma unroll
    for (int u = 0; u < 4; ++u) {
      float4 a = qr[e * 4 + u], b = mr[e * 4 + u];
      s = fmaf(a.x, b.x, s); s = fmaf(a.y, b.y, s);
      s = fmaf(a.z, b.z, s); s = fmaf(a.w, b.w, s);
    }
    s += __shfl_xor(s, 1, 8);
    s += __shfl_xor(s, 2, 8);
    s += __shfl_xor(s, 4, 8);
    if (e == 0) {
      float d2 = (Pq2[q] + Pm2[gidx]) - 2.0f * s;
      float dist = sqrtf(fmaxf(d2, 1e-12f));
      keyx[g] = (((unsigned long long)__float_as_uint(dist)) << 32) | (unsigned)gidx;
    }
  }
  __syncthreads();

  // phase C: exact top-16 of the 32 (wave 0)
  if (t < 64) {
    unsigned long long kk = (t < RESCORE) ? keyx[t] : ~0ull;
    for (int r = 0; r < KSEL; ++r) {
      unsigned long long g = kk;
      #pragma unroll
      for (int o = 1; o < 64; o <<= 1) {
        unsigned long long s = __shfl_xor(g, o);
        g = (s < g) ? s : g;
      }
      if (kk == g) kk = ~0ull;
      if (t == 0) selB[r] = g;
    }
  }
  __syncthreads();

  if (t < KSEL) {
    const float d  = __uint_as_float((unsigned)(selB[t] >> 32));
    const float d0 = __uint_as_float((unsigned)(selB[0] >> 32));
    el[t] = expf(-(d / 0.1f) + (d0 / 0.1f));
  }
  __syncthreads();
  if (t < KSEL) {
    float sum = 0.f;
    #pragma unroll
    for (int i = 0; i < KSEL; ++i) sum += el[i];
    outW[(size_t)q * KSEL + t] = el[t] / sum;
  }

  for (int f4 = t; f4 < KSEL * 32; f4 += 256) {
    int r = f4 >> 5, c4 = f4 & 31;
    int idx = (int)(selB[r] & 0xffffffffu);
    *(float4*)&outO[((size_t)q * KSEL + r) * DIM + c4 * 4] =
        *(const float4*)&memOut[(size_t)idx * DIM + c4 * 4];
  }
}

// ---------------------------------------------------------------------------
extern "C" void kernel_launch(void* const* d_in, const int* in_sizes, int n_in,
                              void* d_out, int out_size, void* d_ws, size_t ws_size,
                              hipStream_t stream)
{
  const float* query   = (const float*)d_in[0];
  const float* W       = (const float*)d_in[1];
  const float* bias    = (const float*)d_in[2];
  const float* mem_emb = (const float*)d_in[3];
  const float* mem_out = (const float*)d_in[4];
  const int B = in_sizes[0] / DIM;   // 2048
  const int N = in_sizes[3] / DIM;   // 100000
  const int N_pad = ((N + MB + 15) / 16) * 16;   // covers last-split tile overrun

  // workspace: Pm fp32 | Pm2 | Pq | Pq2 | splitTop | [Pm bf16 if it fits]
  float* ws  = (float*)d_ws;
  float* Pm  = ws;
  float* Pm2 = Pm + (size_t)N_pad * DIM;
  float* Pq  = Pm2 + N_pad;
  float* Pq2 = Pq + (size_t)B * DIM;
  unsigned* splitTop = (unsigned*)(Pq2 + B);
  unsigned short* Pmbf = (unsigned short*)(splitTop + (size_t)B * NSPLIT * KSEL);
  const size_t need_bf = (size_t)((char*)(Pmbf + (size_t)N_pad * DIM) - (char*)d_ws);
  const bool usebf = ws_size >= need_bf;

  float* outW = (float*)d_out;
  float* outO = outW + (size_t)B * KSEL;

  // 1) Poincare transforms (fp32 exact basis; bf16 copy for scoring if room)
  poincare_k<<<dim3((N + 127) / 128), dim3(512), 0, stream>>>(
      mem_emb, N, W, bias, Pm, Pm2, usebf ? Pmbf : nullptr);
  poincare_k<<<dim3((B + 127) / 128), dim3(512), 0, stream>>>(
      query, B, W, bias, Pq, Pq2, nullptr);

  // 2) bf16-MFMA approx scoring + split top-16
  dim3 grid2(NSPLIT, B / QB);
  if (usebf)
    score_topk_k<true><<<grid2, dim3(512), 0, stream>>>(Pq, Pm, Pm2, Pmbf, N, splitTop);
  else
    score_topk_k<false><<<grid2, dim3(512), 0, stream>>>(Pq, Pm, Pm2, nullptr, N, splitTop);

  // 3) merge + exact rescore + softmax + gather
  finalize_k<<<dim3(B), dim3(256), 0, stream>>>(splitTop, Pq, Pq2, Pm, Pm2,
                                                mem_out, N, outW, outO);
}

// Round 7
// 228.554 us; speedup vs baseline: 12.0110x; 1.1586x over previous
//
#include <hip/hip_runtime.h>
#include <hip/hip_bf16.h>
#include <math.h>

#define DIM 128
#define QB 64
#define MB 128
#define NSPLIT 16
#define KSEL 16
#define KOWN 4
#define RESCORE 32
#define IDXMASK 0x1FFFu
#define KEYMASK 0xFFFFE000u

using bf16x8 = __attribute__((ext_vector_type(8))) short;
using f32x4  = __attribute__((ext_vector_type(4))) float;

__device__ inline unsigned short f2bf(float f) {
  __hip_bfloat16 h = __float2bfloat16(f);   // RNE
  return __builtin_bit_cast(unsigned short, h);
}

__device__ inline f32x4 mfma16(bf16x8 a, bf16x8 b, f32x4 c) {
  return __builtin_amdgcn_mfma_f32_16x16x32_bf16(a, b, c, 0, 0, 0);
}

__device__ inline void gload_lds16(const void* g, void* l) {
  __builtin_amdgcn_global_load_lds(
      (const __attribute__((address_space(1))) void*)g,
      (__attribute__((address_space(3))) void*)l, 16, 0, 0);
}

// ---------------------------------------------------------------------------
// Kernel 1 (fused): Poincare transform for mem rows AND query rows in one grid
//   P = clip_ball(tanh(X @ W^T + b)), P2 = ||P||^2; bf16 copy PRE-SWIZZLED
//   (chunk position = cg ^ (row&7)). Split bases are multiples of MB=128, so
//   global-row swizzle == local-row swizzle in K2 (the R6 bug fix).
// ---------------------------------------------------------------------------
__global__ __launch_bounds__(512) void poincare2_k(
    const float* __restrict__ Xm, int Rm,
    const float* __restrict__ Xq, int Rq,
    const float* __restrict__ W, const float* __restrict__ bias,
    float* __restrict__ Pm, float* __restrict__ Pm2,
    unsigned short* __restrict__ Pmbf,
    float* __restrict__ Pq, float* __restrict__ Pq2, int nbm)
{
  __shared__ float Wl[DIM * DIM];        // 64 KB, swizzled
  __shared__ float nrm[128 * 17];        // partials [row][cg]
  __shared__ float norm2l[128];

  const int t  = threadIdx.x;
  const int cg = t & 15;                 // 0..15 (8 cols each)
  const int rg = t >> 4;                 // 0..31 (rows rg + 32v)

  const bool ismem = (int)blockIdx.x < nbm;
  const float* X = ismem ? Xm : Xq;
  const int    R = ismem ? Rm : Rq;
  float*       P  = ismem ? Pm  : Pq;
  float*       P2 = ismem ? Pm2 : Pq2;
  unsigned short* Pbf = ismem ? Pmbf : nullptr;
  const int rbase = (ismem ? blockIdx.x : (blockIdx.x - nbm)) * 128;

  for (int i = t; i < DIM * 32; i += 512) {
    const int j = i >> 5, c = i & 31;
    const float4 v = *(const float4*)&W[j * DIM + c * 4];
    *(float4*)&Wl[j * DIM + ((c ^ ((j >> 3) & 7)) << 2)] = v;
  }
  float bj[8];
  #pragma unroll
  for (int u = 0; u < 8; ++u) bj[u] = bias[cg * 8 + u];

  const float* xr[4];
  #pragma unroll
  for (int v = 0; v < 4; ++v) {
    int row = rbase + rg + 32 * v;
    if (row > R - 1) row = R - 1;        // clamp; invalid rows never stored
    xr[v] = X + (size_t)row * DIM;
  }
  __syncthreads();

  float acc[4][8];
  #pragma unroll
  for (int v = 0; v < 4; ++v)
    #pragma unroll
    for (int u = 0; u < 8; ++u) acc[v][u] = bj[u];

  #pragma unroll 2
  for (int k4 = 0; k4 < 32; ++k4) {
    float4 xv[4], wv[8];
    #pragma unroll
    for (int v = 0; v < 4; ++v) xv[v] = *(const float4*)&xr[v][k4 * 4];
    #pragma unroll
    for (int u = 0; u < 8; ++u) {
      const int j = cg * 8 + u;
      wv[u] = *(const float4*)&Wl[j * DIM + ((k4 ^ ((j >> 3) & 7)) << 2)];
    }
    #pragma unroll
    for (int v = 0; v < 4; ++v)
      #pragma unroll
      for (int u = 0; u < 8; ++u) {
        acc[v][u] = fmaf(xv[v].x, wv[u].x, acc[v][u]);
        acc[v][u] = fmaf(xv[v].y, wv[u].y, acc[v][u]);
        acc[v][u] = fmaf(xv[v].z, wv[u].z, acc[v][u]);
        acc[v][u] = fmaf(xv[v].w, wv[u].w, acc[v][u]);
      }
  }

  #pragma unroll
  for (int v = 0; v < 4; ++v) {
    float pn = 0.f;
    #pragma unroll
    for (int u = 0; u < 8; ++u) {
      const float th = tanhf(acc[v][u]);
      acc[v][u] = th;
      pn = fmaf(th, th, pn);
    }
    nrm[(rg + 32 * v) * 17 + cg] = pn;
  }
  __syncthreads();
  if (t < 128) {
    float s = 0.f;
    #pragma unroll
    for (int c2 = 0; c2 < 16; ++c2) s += nrm[t * 17 + c2];
    norm2l[t] = s;
    if (rbase + t < R) {
      const float nm = sqrtf(s);
      const float sc = (nm > 0.9f) ? (0.9f / nm) : 1.0f;
      P2[rbase + t] = s * sc * sc;
    }
  }
  __syncthreads();

  #pragma unroll
  for (int v = 0; v < 4; ++v) {
    const int r = rg + 32 * v;
    const int row = rbase + r;
    if (row < R) {
      const float n2 = norm2l[r];
      const float nm = sqrtf(n2);
      const float sc = (nm > 0.9f) ? (0.9f / nm) : 1.0f;
      float o[8];
      #pragma unroll
      for (int u = 0; u < 8; ++u) o[u] = acc[v][u] * sc;
      *(float4*)&P[(size_t)row * DIM + cg * 8]     = make_float4(o[0], o[1], o[2], o[3]);
      *(float4*)&P[(size_t)row * DIM + cg * 8 + 4] = make_float4(o[4], o[5], o[6], o[7]);
      if (Pbf) {
        uint4 pb;
        pb.x = (unsigned)f2bf(o[0]) | ((unsigned)f2bf(o[1]) << 16);
        pb.y = (unsigned)f2bf(o[2]) | ((unsigned)f2bf(o[3]) << 16);
        pb.z = (unsigned)f2bf(o[4]) | ((unsigned)f2bf(o[5]) << 16);
        pb.w = (unsigned)f2bf(o[6]) | ((unsigned)f2bf(o[7]) << 16);
        // pre-swizzled store: chunk position = cg ^ (row&7)
        *(uint4*)&Pmbf[(size_t)row * DIM + ((cg ^ (row & 7)) << 3)] = pb;
      }
    }
  }
}

// ---------------------------------------------------------------------------
// Kernel 2: bf16-MFMA approx scoring + in-register per-lane top-4 selection.
//   Split base = split*splitlen (multiple of MB) -> global row % 8 == local
//   row % 8, so the pre-swizzled Pmbf + local unswizzle at MFMA read agree.
// ---------------------------------------------------------------------------
template<bool USEBF>
__global__ __launch_bounds__(512, 4) void score_topk_k(
    const float* __restrict__ Pq,
    const float* __restrict__ Pm, const float* __restrict__ Pm2,
    const unsigned short* __restrict__ Pmbf,
    int N, int splitlen, unsigned* __restrict__ splitTop)
{
  __shared__ __align__(16) unsigned short Ml[2][MB * DIM];  // 2 x 32 KB swizzled
  __shared__ float m2p2l[2][MB];

  const int t = threadIdx.x;
  const int lane = t & 63;
  const int w = t >> 6, wr = w >> 2, wc = w & 3;
  const int split = blockIdx.x;
  const int qbase = blockIdx.y * QB;
  const int mlo = split * splitlen;                 // multiple of MB
  const int mhi = min(mlo + splitlen, N);

  // persistent Q fragments (A operand): row = lane&15, k-chunk = (lane>>4)*8
  bf16x8 qf[2][4];
  #pragma unroll
  for (int s = 0; s < 2; ++s) {
    const int qrow = qbase + (wr * 2 + s) * 16 + (lane & 15);
    #pragma unroll
    for (int ks = 0; ks < 4; ++ks) {
      const float* src = &Pq[(size_t)qrow * DIM + ks * 32 + (lane >> 4) * 8];
      float4 lo = *(const float4*)src;
      float4 hi = *(const float4*)(src + 4);
      bf16x8 v;
      v[0] = (short)f2bf(lo.x); v[1] = (short)f2bf(lo.y);
      v[2] = (short)f2bf(lo.z); v[3] = (short)f2bf(lo.w);
      v[4] = (short)f2bf(hi.x); v[5] = (short)f2bf(hi.y);
      v[6] = (short)f2bf(hi.z); v[7] = (short)f2bf(hi.w);
      qf[s][ks] = v;
    }
  }

  uint4 sv[4];                                   // !USEBF fallback only
  auto stage_issue = [&](int mbase, int buf) {
    if constexpr (USEBF) {
      #pragma unroll
      for (int i = 0; i < 4; ++i) {
        const int rr = w * 16 + i * 4;
        const unsigned short* src = Pmbf +
            (size_t)(mbase + rr + (lane >> 4)) * DIM + ((lane & 15) << 3);
        gload_lds16(src, &Ml[buf][rr * DIM]);    // linear dest; src pre-swizzled
      }
    } else {
      const int r = t >> 2, qt = t & 3;
      const float* src = Pm + (size_t)(mbase + r) * DIM + qt * 32;
      #pragma unroll
      for (int u = 0; u < 4; ++u) {
        float4 a = *(const float4*)(src + u * 8);
        float4 b = *(const float4*)(src + u * 8 + 4);
        uint4 o;
        o.x = (unsigned)f2bf(a.x) | ((unsigned)f2bf(a.y) << 16);
        o.y = (unsigned)f2bf(a.z) | ((unsigned)f2bf(a.w) << 16);
        o.z = (unsigned)f2bf(b.x) | ((unsigned)f2bf(b.y) << 16);
        o.w = (unsigned)f2bf(b.z) | ((unsigned)f2bf(b.w) << 16);
        sv[u] = o;
      }
    }
  };
  auto stage_write_fb = [&](int buf) {
    if constexpr (!USEBF) {
      const int r = t >> 2, qt = t & 3;
      char* base = (char*)&Ml[buf][0] + r * 256;
      #pragma unroll
      for (int u = 0; u < 4; ++u)
        *(uint4*)(base + (((qt * 4 + u) ^ (r & 7)) << 4)) = sv[u];
    }
  };

  // prologue: tile 0 into buf 0
  float m2n = __int_as_float(0x7f800000);
  stage_issue(mlo, 0);
  if (t < MB) {
    const int gr = mlo + t;
    if (gr < mhi) m2n = Pm2[gr] + 2.0f;
  }
  stage_write_fb(0);
  if (t < MB) m2p2l[0][t] = m2n;
  __syncthreads();

  unsigned keys[2][4][KOWN];
  #pragma unroll
  for (int s = 0; s < 2; ++s)
    #pragma unroll
    for (int r = 0; r < 4; ++r)
      #pragma unroll
      for (int i = 0; i < KOWN; ++i) keys[s][r][i] = 0xFFFFFFFFu;

  const int ntiles = (mhi - mlo + MB - 1) / MB;

  for (int tile = 0; tile < ntiles; ++tile) {
    const int cur = tile & 1;
    const bool more = (tile + 1 < ntiles);

    // issue next-tile loads first: they drain at this tile's ending barrier
    if (more) {
      stage_issue(mlo + (tile + 1) * MB, cur ^ 1);
      m2n = __int_as_float(0x7f800000);
      if (t < MB) {
        const int gr = mlo + (tile + 1) * MB + t;
        if (gr < mhi) m2n = Pm2[gr] + 2.0f;
      }
    }

    const float m2a = m2p2l[cur][wc * 32 + (lane & 15)];
    const float m2b = m2p2l[cur][wc * 32 + 16 + (lane & 15)];

    f32x4 acc[2][2];
    #pragma unroll
    for (int s = 0; s < 2; ++s)
      #pragma unroll
      for (int n = 0; n < 2; ++n) acc[s][n] = (f32x4){0.f, 0.f, 0.f, 0.f};

    __builtin_amdgcn_s_setprio(1);
    #pragma unroll
    for (int ks = 0; ks < 4; ++ks) {
      #pragma unroll
      for (int n = 0; n < 2; ++n) {
        const int row = (wc * 2 + n) * 16 + (lane & 15);
        const int cb  = (ks * 64 + (lane >> 4) * 16) ^ ((row & 7) << 4);
        bf16x8 bfr = *(const bf16x8*)((const char*)&Ml[cur][0] + row * 256 + cb);
        acc[0][n] = mfma16(qf[0][ks], bfr, acc[0][n]);
        acc[1][n] = mfma16(qf[1][ks], bfr, acc[1][n]);
      }
    }
    __builtin_amdgcn_s_setprio(0);

    // in-register selection: rank = m2+2-2*dot; key = (bits&MASK)|m_local
    const unsigned ibase = (unsigned)(tile * MB + wc * 32 + (lane & 15));
    #pragma unroll
    for (int s = 0; s < 2; ++s)
      #pragma unroll
      for (int n = 0; n < 2; ++n) {
        const float m2v = n ? m2b : m2a;
        const unsigned idxn = ibase + n * 16;
        #pragma unroll
        for (int r = 0; r < 4; ++r) {
          const float d2 = fmaf(-2.0f, acc[s][n][r], m2v);
          unsigned c = (__float_as_uint(d2) & KEYMASK) | idxn;
          #pragma unroll
          for (int i = 0; i < KOWN; ++i) {
            const unsigned lo = c < keys[s][r][i] ? c : keys[s][r][i];
            c = c < keys[s][r][i] ? keys[s][r][i] : c;
            keys[s][r][i] = lo;
          }
        }
      }

    if (more) {
      stage_write_fb(cur ^ 1);
      if (t < MB) m2p2l[cur ^ 1][t] = m2n;
    }
    __syncthreads();   // drains vmcnt (gload_lds) + LDS writes; frees Ml[cur]
  }

  // emission: per (s,r) q-slot, 16-lane tournament -> sorted top-8 of 64 keys
  // (keys unique across lanes: low idx bits contain lane&15)
  #pragma unroll
  for (int s = 0; s < 2; ++s)
    #pragma unroll
    for (int r = 0; r < 4; ++r) {
      unsigned k0 = keys[s][r][0], k1 = keys[s][r][1];
      unsigned k2 = keys[s][r][2], k3 = keys[s][r][3];
      unsigned out = 0xFFFFFFFFu;
      for (int round = 0; round < 8; ++round) {
        unsigned g = k0, o;
        o = __shfl_xor(g, 1, 16); g = o < g ? o : g;
        o = __shfl_xor(g, 2, 16); g = o < g ? o : g;
        o = __shfl_xor(g, 4, 16); g = o < g ? o : g;
        o = __shfl_xor(g, 8, 16); g = o < g ? o : g;
        const bool mine = (k0 == g);
        k0 = mine ? k1 : k0;
        k1 = mine ? k2 : k1;
        k2 = mine ? k3 : k2;
        k3 = mine ? 0xFFFFFFFFu : k3;
        if ((lane & 15) == round) out = g;
      }
      const int q = qbase + wr * 32 + s * 16 + (lane >> 4) * 4 + r;
      if ((lane & 15) < 8)
        splitTop[(((size_t)q * NSPLIT + split) * 4 + wc) * 8 + (lane & 15)] = out;
    }
}

// ---------------------------------------------------------------------------
// Kernel 3: merge 512 candidates/query -> approx top-32 -> EXACT fp32 rescore
//           -> exact top-16, softmax weights, gather outcomes.
// ---------------------------------------------------------------------------
__global__ __launch_bounds__(256) void finalize_k(
    const unsigned* __restrict__ splitTop,
    const float* __restrict__ Pq, const float* __restrict__ Pq2,
    const float* __restrict__ Pm, const float* __restrict__ Pm2,
    const float* __restrict__ memOut, int N, int splitlen,
    float* __restrict__ outW, float* __restrict__ outO)
{
  const int q = blockIdx.x;
  const int t = threadIdx.x;
  __shared__ unsigned selKey[RESCORE];
  __shared__ int      selSrc[RESCORE];
  __shared__ unsigned long long keyx[RESCORE];
  __shared__ unsigned long long selB[KSEL];
  __shared__ float el[KSEL];

  // phase A: approx top-32 of 512 keys; lane t owns group t = split*4+wc,
  // whose 8 keys arrive SORTED ascending -> head is the lane min.
  if (t < 64) {
    const unsigned* gp = splitTop + (size_t)q * (NSPLIT * 4 * 8) + t * 8;
    unsigned k0 = gp[0], k1 = gp[1], k2 = gp[2], k3 = gp[3];
    unsigned k4 = gp[4], k5 = gp[5], k6 = gp[6], k7 = gp[7];
    for (int r = 0; r < RESCORE; ++r) {
      unsigned g = k0, o;
      #pragma unroll
      for (int st = 1; st < 64; st <<= 1) { o = __shfl_xor(g, st); g = o < g ? o : g; }
      unsigned long long mask = __ballot(k0 == g);
      const int fl = __ffsll((unsigned long long)mask) - 1;
      if (t == fl) {
        selKey[r] = g;
        selSrc[r] = t;                       // group id -> split = t>>2
        k0 = k1; k1 = k2; k2 = k3; k3 = k4;
        k4 = k5; k5 = k6; k6 = k7; k7 = 0xFFFFFFFFu;
      }
    }
  }
  __syncthreads();

  // phase B: exact fp32 rescore of 32 candidates, 8 threads each
  {
    const int g = t >> 3, e = t & 7;
    const int gidx = (selSrc[g] >> 2) * splitlen + (int)(selKey[g] & IDXMASK);
    const float4* qr = (const float4*)&Pq[(size_t)q * DIM];
    const float4* mr = (const float4*)&Pm[(size_t)gidx * DIM];
    float s = 0.f;
    #pragma unroll
    for (int u = 0; u < 4; ++u) {
      float4 a = qr[e * 4 + u], b = mr[e * 4 + u];
      s = fmaf(a.x, b.x, s); s = fmaf(a.y, b.y, s);
      s = fmaf(a.z, b.z, s); s = fmaf(a.w, b.w, s);
    }
    s += __shfl_xor(s, 1, 8);
    s += __shfl_xor(s, 2, 8);
    s += __shfl_xor(s, 4, 8);
    if (e == 0) {
      float d2 = (Pq2[q] + Pm2[gidx]) - 2.0f * s;
      float dist = sqrtf(fmaxf(d2, 1e-12f));
      keyx[g] = (((unsigned long long)__float_as_uint(dist)) << 32) | (unsigned)gidx;
    }
  }
  __syncthreads();

  // phase C: exact top-16 of the 32 (wave 0)
  if (t < 64) {
    unsigned long long kk = (t < RESCORE) ? keyx[t] : ~0ull;
    for (int r = 0; r < KSEL; ++r) {
      unsigned long long g = kk;
      #pragma unroll
      for (int o = 1; o < 64; o <<= 1) {
        unsigned long long s = __shfl_xor(g, o);
        g = (s < g) ? s : g;
      }
      if (kk == g) kk = ~0ull;
      if (t == 0) selB[r] = g;
    }
  }
  __syncthreads();

  if (t < KSEL) {
    const float d  = __uint_as_float((unsigned)(selB[t] >> 32));
    const float d0 = __uint_as_float((unsigned)(selB[0] >> 32));
    el[t] = expf(-(d / 0.1f) + (d0 / 0.1f));
  }
  __syncthreads();
  if (t < KSEL) {
    float sum = 0.f;
    #pragma unroll
    for (int i = 0; i < KSEL; ++i) sum += el[i];
    outW[(size_t)q * KSEL + t] = el[t] / sum;
  }

  for (int f4 = t; f4 < KSEL * 32; f4 += 256) {
    int r = f4 >> 5, c4 = f4 & 31;
    int idx = (int)(selB[r] & 0xffffffffu);
    *(float4*)&outO[((size_t)q * KSEL + r) * DIM + c4 * 4] =
        *(const float4*)&memOut[(size_t)idx * DIM + c4 * 4];
  }
}

// ---------------------------------------------------------------------------
extern "C" void kernel_launch(void* const* d_in, const int* in_sizes, int n_in,
                              void* d_out, int out_size, void* d_ws, size_t ws_size,
                              hipStream_t stream)
{
  const float* query   = (const float*)d_in[0];
  const float* W       = (const float*)d_in[1];
  const float* bias    = (const float*)d_in[2];
  const float* mem_emb = (const float*)d_in[3];
  const float* mem_out = (const float*)d_in[4];
  const int B = in_sizes[0] / DIM;   // 2048
  const int N = in_sizes[3] / DIM;   // 100000
  const int N_pad = ((N + MB + 15) / 16) * 16;   // covers last-split tile overrun

  // tile-aligned split length: mlo = split*splitlen is a multiple of MB
  const int splitlen = ((N + NSPLIT * MB - 1) / (NSPLIT * MB)) * MB;   // 6272

  // workspace: Pm fp32 | Pm2 | Pq | Pq2 | splitTop(512/q) | [Pm bf16 if room]
  float* ws  = (float*)d_ws;
  float* Pm  = ws;
  float* Pm2 = Pm + (size_t)N_pad * DIM;
  float* Pq  = Pm2 + N_pad;
  float* Pq2 = Pq + (size_t)B * DIM;
  unsigned* splitTop = (unsigned*)(Pq2 + B);
  unsigned short* Pmbf = (unsigned short*)(splitTop + (size_t)B * NSPLIT * 4 * 8);
  const size_t need_bf = (size_t)((char*)(Pmbf + (size_t)N_pad * DIM) - (char*)d_ws);
  const bool usebf = ws_size >= need_bf;

  float* outW = (float*)d_out;
  float* outO = outW + (size_t)B * KSEL;

  // 1) fused Poincare transforms (fp32 exact basis; pre-swizzled bf16 copy)
  const int nbm = (N + 127) / 128;
  const int nbq = (B + 127) / 128;
  poincare2_k<<<dim3(nbm + nbq), dim3(512), 0, stream>>>(
      mem_emb, N, query, B, W, bias, Pm, Pm2, usebf ? Pmbf : nullptr, Pq, Pq2, nbm);

  // 2) bf16-MFMA approx scoring + per-(q,split,wc) top-8
  dim3 grid2(NSPLIT, B / QB);
  if (usebf)
    score_topk_k<true><<<grid2, dim3(512), 0, stream>>>(Pq, Pm, Pm2, Pmbf, N,
                                                        splitlen, splitTop);
  else
    score_topk_k<false><<<grid2, dim3(512), 0, stream>>>(Pq, Pm, Pm2, nullptr, N,
                                                         splitlen, splitTop);

  // 3) merge + exact rescore + softmax + gather
  finalize_k<<<dim3(B), dim3(256), 0, stream>>>(splitTop, Pq, Pq2, Pm, Pm2,
                                                mem_out, N, splitlen, outW, outO);
}